// Round 6
// baseline (7964.240 us; speedup 1.0000x reference)
//
#include <hip/hip_runtime.h>
#include <hip/hip_bf16.h>
#include <cstddef>

#define NN 100000
#define EE 3200000
static const float EF = 3200000.0f;

// ---------- helpers ----------

__device__ __forceinline__ float wsum(float v) {
  #pragma unroll
  for (int off = 32; off > 0; off >>= 1) v += __shfl_down(v, off, 64);
  return v;  // lane 0 holds wave total
}

// block-level reduce of 32 sums + 32 sumsq -> global atomics. red = shared float[256].
__device__ __forceinline__ void reduce64(float sum[32], float ssq[32], float* red,
                                         float* __restrict__ gsum, float* __restrict__ gssq) {
  const int wid = threadIdx.x >> 6, lane = threadIdx.x & 63;
  #pragma unroll
  for (int j = 0; j < 32; j++) {
    float a = wsum(sum[j]);
    float b = wsum(ssq[j]);
    if (lane == 0) { red[wid * 64 + j] = a; red[wid * 64 + 32 + j] = b; }
  }
  __syncthreads();
  if (threadIdx.x < 64) {
    float t = red[threadIdx.x] + red[64 + threadIdx.x] + red[128 + threadIdx.x] + red[192 + threadIdx.x];
    if (threadIdx.x < 32) unsafeAtomicAdd(&gsum[threadIdx.x], t);
    else                  unsafeAtomicAdd(&gssq[threadIdx.x - 32], t);
  }
}

__device__ __forceinline__ void loadrow(const float* __restrict__ xp, int s, float in[13]) {
  const float4* xr = reinterpret_cast<const float4*>(xp + (size_t)s * 12);
  float4 r0 = xr[0], r1 = xr[1], r2 = xr[2];
  in[0]=r0.x; in[1]=r0.y; in[2]=r0.z; in[3]=r0.w; in[4]=r1.x; in[5]=r1.y; in[6]=r1.z; in[7]=r1.w;
  in[8]=r2.x; in[9]=r2.y; in[10]=r2.z;
}

// ---------- setup kernels ----------

// w2tf[j][k] = d_j * w1b[k][j] (d_j = sign(g1b_j)); b1bf[j] = d_j*b1b[j];
// w2aT[j][0..42]+bias at 43; wpaT[j][0..10]+bias at 11
__global__ __launch_bounds__(256) void k_wprep(const float* __restrict__ w1b,
    const float* __restrict__ b1b, const float* __restrict__ g1b,
    const float* __restrict__ w2a, const float* __restrict__ b2a,
    const float* __restrict__ wpa, const float* __restrict__ bpa,
    float* __restrict__ w2tf, float* __restrict__ b1bf,
    float* __restrict__ w2aT, float* __restrict__ wpaT) {
  int t = threadIdx.x;
  for (int i = t; i < 1024; i += 256) {
    int j = i >> 5, k = i & 31;
    float d = (g1b[j] >= 0.f) ? 1.f : -1.f;
    w2tf[j * 32 + k] = d * w1b[k * 32 + j];
  }
  for (int i = t; i < 32 * 43; i += 256) { int j = i & 31, k = i >> 5; w2aT[j * 44 + k] = w2a[k * 32 + j]; }
  for (int i = t; i < 32 * 11; i += 256) { int j = i & 31, k = i >> 5; wpaT[j * 12 + k] = wpa[k * 32 + j]; }
  if (t < 32) {
    float d = (g1b[t] >= 0.f) ? 1.f : -1.f;
    b1bf[t] = d * b1b[t];
    w2aT[t * 44 + 43] = b2a[t];
    wpaT[t * 12 + 11] = bpa[t];
  }
}

// one edge pass (4 edges/thread/iter): dst counts, src out-degrees, per-src ea sums, global ea moments
__global__ __launch_bounds__(256) void k_prep(const int* __restrict__ dst, const int* __restrict__ src,
    const float* __restrict__ ea, int* __restrict__ cnt, int* __restrict__ deg,
    float* __restrict__ sea, float* __restrict__ cmom) {
  float p0 = 0, p1 = 0, p2 = 0, p3 = 0, p4 = 0;
  const int S = gridDim.x * 256;
  for (int g = blockIdx.x * 256 + threadIdx.x; g < EE / 4; g += S) {
    int4 d4 = reinterpret_cast<const int4*>(dst)[g];
    int4 s4 = reinterpret_cast<const int4*>(src)[g];
    float4 e0 = reinterpret_cast<const float4*>(ea)[2 * g];
    float4 e1 = reinterpret_cast<const float4*>(ea)[2 * g + 1];
    atomicAdd(&cnt[d4.x], 1); atomicAdd(&cnt[d4.y], 1); atomicAdd(&cnt[d4.z], 1); atomicAdd(&cnt[d4.w], 1);
    atomicAdd(&deg[s4.x], 1); atomicAdd(&deg[s4.y], 1); atomicAdd(&deg[s4.z], 1); atomicAdd(&deg[s4.w], 1);
    unsafeAtomicAdd(&sea[2 * s4.x], e0.x); unsafeAtomicAdd(&sea[2 * s4.x + 1], e0.y);
    unsafeAtomicAdd(&sea[2 * s4.y], e0.z); unsafeAtomicAdd(&sea[2 * s4.y + 1], e0.w);
    unsafeAtomicAdd(&sea[2 * s4.z], e1.x); unsafeAtomicAdd(&sea[2 * s4.z + 1], e1.y);
    unsafeAtomicAdd(&sea[2 * s4.w], e1.z); unsafeAtomicAdd(&sea[2 * s4.w + 1], e1.w);
    p0 += e0.x * e0.x + e0.z * e0.z + e1.x * e1.x + e1.z * e1.z;
    p1 += e0.x * e0.y + e0.z * e0.w + e1.x * e1.y + e1.z * e1.w;
    p2 += e0.y * e0.y + e0.w * e0.w + e1.y * e1.y + e1.w * e1.w;
    p3 += e0.x + e0.z + e1.x + e1.z;
    p4 += e0.y + e0.w + e1.y + e1.w;
  }
  p0 = wsum(p0); p1 = wsum(p1); p2 = wsum(p2); p3 = wsum(p3); p4 = wsum(p4);
  if ((threadIdx.x & 63) == 0) {
    unsafeAtomicAdd(&cmom[0], p0); unsafeAtomicAdd(&cmom[1], p1); unsafeAtomicAdd(&cmom[2], p2);
    unsafeAtomicAdd(&cmom[3], p3); unsafeAtomicAdd(&cmom[4], p4);
  }
}

__global__ __launch_bounds__(1024) void k_scan(const int* __restrict__ cnt,
                                               int* __restrict__ starts, int* __restrict__ fill) {
  __shared__ int part[1024];
  const int T = 1024, CH = (NN + T - 1) / T;
  int t = threadIdx.x;
  int lo = t * CH, hi = min(lo + CH, NN);
  int s = 0;
  for (int i = lo; i < hi; i++) s += cnt[i];
  part[t] = s; __syncthreads();
  for (int off = 1; off < T; off <<= 1) {
    int v = (t >= off) ? part[t - off] : 0;
    __syncthreads();
    part[t] += v;
    __syncthreads();
  }
  int run = part[t] - s;  // exclusive prefix
  for (int i = lo; i < hi; i++) { starts[i] = run; fill[i] = run; run += cnt[i]; }
  if (t == T - 1) starts[NN] = EE;
}

// scatter packed 16B edge records (src, ea.x, ea.y, 0) into CSR order
__global__ __launch_bounds__(256) void k_scatter(const int* __restrict__ dst, const int* __restrict__ src,
    const float* __restrict__ ea, int* __restrict__ fill, int4* __restrict__ edg) {
  const int S = gridDim.x * 256;
  for (int g = blockIdx.x * 256 + threadIdx.x; g < EE / 4; g += S) {
    int4 d4 = reinterpret_cast<const int4*>(dst)[g];
    int4 s4 = reinterpret_cast<const int4*>(src)[g];
    float4 e0 = reinterpret_cast<const float4*>(ea)[2 * g];
    float4 e1 = reinterpret_cast<const float4*>(ea)[2 * g + 1];
    int p0 = atomicAdd(&fill[d4.x], 1);
    edg[p0] = make_int4(s4.x, __float_as_int(e0.x), __float_as_int(e0.y), 0);
    int p1 = atomicAdd(&fill[d4.y], 1);
    edg[p1] = make_int4(s4.y, __float_as_int(e0.z), __float_as_int(e0.w), 0);
    int p2 = atomicAdd(&fill[d4.z], 1);
    edg[p2] = make_int4(s4.z, __float_as_int(e1.x), __float_as_int(e1.y), 0);
    int p3 = atomicAdd(&fill[d4.w], 1);
    edg[p3] = make_int4(s4.w, __float_as_int(e1.z), __float_as_int(e1.w), 0);
  }
}

// padded node rows: xp[n][0..9]=x cols 0..9, [10]=x col10 (current), [11]=0
__global__ __launch_bounds__(256) void k_xp(const float* __restrict__ x, float* __restrict__ xp) {
  int n = blockIdx.x * 256 + threadIdx.x;
  if (n >= NN) return;
  float v[11];
  #pragma unroll
  for (int k = 0; k < 11; k++) v[k] = x[(size_t)n * 11 + k];
  float4* o = reinterpret_cast<float4*>(xp + (size_t)n * 12);
  o[0] = make_float4(v[0], v[1], v[2], v[3]);
  o[1] = make_float4(v[4], v[5], v[6], v[7]);
  o[2] = make_float4(v[8], v[9], v[10], 0.f);
}

// ---------- per-conv: input moments (node pass, replaces a P1 edge pass) ----------
// mom layout: [0..10]=S_x (deg-weighted), [11..76]=sxx upper-tri(11), [77..98]=sxe
__global__ __launch_bounds__(256) void k_mom(const float* __restrict__ xp, const int* __restrict__ deg,
                                             const float* __restrict__ sea, float* __restrict__ mom) {
  const int n = blockIdx.x * 256 + threadIdx.x;
  const int lane = threadIdx.x & 63;
  float v[11]; float w = 0.f; float sx = 0.f, sy = 0.f;
  #pragma unroll
  for (int k = 0; k < 11; k++) v[k] = 0.f;
  if (n < NN) {
    w = (float)deg[n];
    loadrow(xp, n, v);
    sx = sea[2 * n]; sy = sea[2 * n + 1];
  }
  int ch = 0;
  #pragma unroll
  for (int a = 0; a < 11; a++) {
    float r = wsum(w * v[a]);
    if (lane == 0) unsafeAtomicAdd(&mom[ch], r);
    ch++;
  }
  #pragma unroll
  for (int a = 0; a < 11; a++) {
    #pragma unroll
    for (int b = a; b < 11; b++) {
      float r = wsum(w * v[a] * v[b]);
      if (lane == 0) unsafeAtomicAdd(&mom[ch], r);
      ch++;
    }
  }
  #pragma unroll
  for (int a = 0; a < 11; a++) {
    float rx = wsum(v[a] * sx);
    if (lane == 0) unsafeAtomicAdd(&mom[ch], rx);
    ch++;
    float ry = wsum(v[a] * sy);
    if (lane == 0) unsafeAtomicAdd(&mom[ch], ry);
    ch++;
  }
}

__device__ __forceinline__ float msym(const float* mom, const float* cmom, int k, int l) {
  int a = min(k, l), b = max(k, l);
  if (b < 11) return mom[11 + a * 11 - a * (a - 1) / 2 + (b - a)];
  if (a < 11) return mom[77 + a * 2 + (b - 11)];
  return cmom[(a - 11) + (b - 11)];
}

// layer-1 BN params from moments; emit FOLDED transposed weights w1f[j][0..12]+bias[13]
// plus compact edge-attr weight arrays wexy[0..31]=A*w[11], wexy[32..63]=A*w[12]; zero mom.
__global__ void k_fin1(float* __restrict__ mom, const float* __restrict__ cmom,
    const float* __restrict__ w1a, const float* __restrict__ b1a,
    const float* __restrict__ g1a, const float* __restrict__ be1a,
    float* __restrict__ w1f, float* __restrict__ wexy) {
  int j = threadIdx.x;  // 32 threads
  float w[13], S[13];
  #pragma unroll
  for (int k = 0; k < 13; k++) w[k] = w1a[k * 32 + j];
  #pragma unroll
  for (int k = 0; k < 11; k++) S[k] = mom[k];
  S[11] = cmom[3]; S[12] = cmom[4];
  float lin = 0.f;
  #pragma unroll
  for (int k = 0; k < 13; k++) lin = fmaf(w[k], S[k], lin);
  float quad = 0.f;
  #pragma unroll
  for (int k = 0; k < 13; k++)
    #pragma unroll
    for (int l = 0; l < 13; l++) quad = fmaf(w[k] * w[l], msym(mom, cmom, k, l), quad);
  const float invE = 1.f / EF;
  float b = b1a[j];
  float mean = fmaf(lin, invE, b);
  float ey2 = (quad + 2.f * b * lin) * invE + b * b;
  float var = fmaxf(ey2 - mean * mean, 0.f);
  float A = g1a[j] * rsqrtf(var + 1e-5f);
  float C = be1a[j] - mean * A;
  #pragma unroll
  for (int k = 0; k < 13; k++) w1f[j * 16 + k] = A * w[k];
  w1f[j * 16 + 13] = fmaf(A, b, C);
  w1f[j * 16 + 14] = 0.f; w1f[j * 16 + 15] = 0.f;
  wexy[j] = A * w[11];
  wexy[32 + j] = A * w[12];
  __syncthreads();
  for (int i = j; i < 128; i += 32) mom[i] = 0.f;
}

// P[n][32] = folded layer-1 pre-activation from node features only (edge attrs added per edge)
__global__ __launch_bounds__(256) void k_P(const float* __restrict__ xp, const float* __restrict__ w1f,
                                           float* __restrict__ P) {
  const int n = blockIdx.x * 256 + threadIdx.x;
  if (n >= NN) return;
  float xv[11];
  loadrow(xp, n, xv);
  float4* op = reinterpret_cast<float4*>(P + (size_t)n * 32);
  #pragma unroll
  for (int jj = 0; jj < 8; jj++) {
    float o[4];
    #pragma unroll
    for (int u = 0; u < 4; u++) {
      int j = 4 * jj + u;
      const float* wr = w1f + j * 16;
      float acc = wr[13];
      #pragma unroll
      for (int k = 0; k < 11; k++) acc = fmaf(xv[k], wr[k], acc);
      o[u] = acc;
    }
    op[jj] = make_float4(o[0], o[1], o[2], o[3]);
  }
}

// ---------- fused edge pass: wave-sliced channels, 2 lanes/node, decoupled depth-2 pipeline ----------
// wave s handles channels [8s,8s+8); lanes 0-31 = nodes (parity 0), lanes 32-63 = same nodes (parity 1).
// Records for iterations i (rA) and i+1 (rB) are held in registers; at iteration i we issue the
// record load for i+2 and the P-row loads for rB (already resident -> no dependent waitcnt).
// The new loads' first consumers are after the ~370-instr compute block -> latency hidden.
__global__ __launch_bounds__(256, 4) void k_fusedagg(
    const int* __restrict__ starts, const int4* __restrict__ edg,
    const float* __restrict__ P, const float* __restrict__ wexy,
    const float* __restrict__ w2tf, const float* __restrict__ b1bf,
    float* __restrict__ tzb, float* __restrict__ gms, float* __restrict__ gzq) {
  const int lane = threadIdx.x & 63;
  const int s = __builtin_amdgcn_readfirstlane(threadIdx.x >> 6);  // slice 0..3, SGPR-uniform
  const int nl = lane & 31, q = lane >> 5;
  const int n = blockIdx.x * 32 + nl;
  float tz[8], zq[8], ms8[8];
  #pragma unroll
  for (int i = 0; i < 8; i++) { tz[i] = -3.0e38f; zq[i] = 0.f; ms8[i] = 0.f; }
  int lo = 0, hi = 0;
  if (n < NN) { lo = starts[n]; hi = starts[n + 1]; }
  const float* wsl = w2tf + (size_t)(8 * s) * 32;   // uniform slice base
  float bz[8];
  #pragma unroll
  for (int i = 0; i < 8; i++) bz[i] = b1bf[8 * s + i];

  int sl = lo + q;
  int4 rA = make_int4(0, 0, 0, 0), rB = make_int4(0, 0, 0, 0);
  if (sl < hi) rA = edg[sl];
  if (sl + 2 < hi) rB = edg[sl + 2];
  float4 pc0, pc1, pc2, pc3, pc4, pc5, pc6, pc7;
  if (sl < hi) {
    const float4* pr = reinterpret_cast<const float4*>(P + (size_t)rA.x * 32);
    pc0 = pr[0]; pc1 = pr[1]; pc2 = pr[2]; pc3 = pr[3];
    pc4 = pr[4]; pc5 = pr[5]; pc6 = pr[6]; pc7 = pr[7];
  }
  while (sl < hi) {
    // ---- issue independent prefetches FIRST (no deps on current compute) ----
    int4 rN = rB;
    if (sl + 4 < hi) rN = edg[sl + 4];
    float4 pn0 = pc0, pn1 = pc1, pn2 = pc2, pn3 = pc3, pn4 = pc4, pn5 = pc5, pn6 = pc6, pn7 = pc7;
    if (sl + 2 < hi) {   // rB already resident: P loads issue with no waitcnt
      const float4* pr = reinterpret_cast<const float4*>(P + (size_t)rB.x * 32);
      pn0 = pr[0]; pn1 = pr[1]; pn2 = pr[2]; pn3 = pr[3];
      pn4 = pr[4]; pn5 = pr[5]; pn6 = pr[6]; pn7 = pr[7];
    }
    // ---- compute current edge (rA, pc*) ----
    const float ex = __int_as_float(rA.y), ey = __int_as_float(rA.z);
    float z[8];
    #pragma unroll
    for (int i = 0; i < 8; i++) z[i] = bz[i];
    #define FA_STEP(JJ, V)                                                              \
    {                                                                                   \
      float m0 = fmaxf(0.f, fmaf(ex, wexy[4*JJ+0], fmaf(ey, wexy[32+4*JJ+0], V.x)));    \
      float m1 = fmaxf(0.f, fmaf(ex, wexy[4*JJ+1], fmaf(ey, wexy[32+4*JJ+1], V.y)));    \
      float m2 = fmaxf(0.f, fmaf(ex, wexy[4*JJ+2], fmaf(ey, wexy[32+4*JJ+2], V.z)));    \
      float m3 = fmaxf(0.f, fmaf(ex, wexy[4*JJ+3], fmaf(ey, wexy[32+4*JJ+3], V.w)));    \
      if ((JJ >> 1) == s) {                                                             \
        const int b = 4 * (JJ & 1);                                                     \
        ms8[b + 0] += m0; ms8[b + 1] += m1; ms8[b + 2] += m2; ms8[b + 3] += m3;         \
      }                                                                                 \
      _Pragma("unroll")                                                                 \
      for (int i = 0; i < 8; i++) {                                                     \
        z[i] = fmaf(m0, wsl[i * 32 + 4*JJ + 0], z[i]);                                  \
        z[i] = fmaf(m1, wsl[i * 32 + 4*JJ + 1], z[i]);                                  \
        z[i] = fmaf(m2, wsl[i * 32 + 4*JJ + 2], z[i]);                                  \
        z[i] = fmaf(m3, wsl[i * 32 + 4*JJ + 3], z[i]);                                  \
      }                                                                                 \
    }
    FA_STEP(0, pc0) FA_STEP(1, pc1) FA_STEP(2, pc2) FA_STEP(3, pc3)
    FA_STEP(4, pc4) FA_STEP(5, pc5) FA_STEP(6, pc6) FA_STEP(7, pc7)
    #undef FA_STEP
    #pragma unroll
    for (int i = 0; i < 8; i++) {
      tz[i] = fmaxf(tz[i], z[i]);
      zq[i] = fmaf(z[i], z[i], zq[i]);
    }
    // ---- rotate pipeline ----
    rA = rB; rB = rN;
    pc0 = pn0; pc1 = pn1; pc2 = pn2; pc3 = pn3; pc4 = pn4; pc5 = pn5; pc6 = pn6; pc7 = pn7;
    sl += 2;
  }
  // combine parity pair (lane <-> lane^32)
  #pragma unroll
  for (int i = 0; i < 8; i++) tz[i] = fmaxf(tz[i], __shfl_xor(tz[i], 32, 64));
  if (q == 0 && n < NN) {
    float4* ot = reinterpret_cast<float4*>(tzb + (size_t)n * 32 + 8 * s);
    ot[0] = make_float4(tz[0], tz[1], tz[2], tz[3]);
    ot[1] = make_float4(tz[4], tz[5], tz[6], tz[7]);
  }
  // stats: ms8 / zq for this wave's 8 channels
  #pragma unroll
  for (int i = 0; i < 8; i++) {
    float a = wsum(ms8[i]);
    if (lane == 0) unsafeAtomicAdd(&gms[8 * s + i], a);
  }
  #pragma unroll
  for (int i = 0; i < 8; i++) {
    float b = wsum(zq[i]);
    if (lane == 0) unsafeAtomicAdd(&gzq[8 * s + i], b);
  }
}

// layer-2 BN: zs_j = w1b[:,j]·ms + E*b1b_j; A2d = A2*sign(g1b); zero ms/zq
__global__ void k_fin2(float* __restrict__ ms, float* __restrict__ zq,
    const float* __restrict__ w1b, const float* __restrict__ b1b,
    const float* __restrict__ g1b, const float* __restrict__ be1b,
    float* __restrict__ A2d, float* __restrict__ C2) {
  __shared__ float sm[32];
  int j = threadIdx.x;  // 32 threads
  sm[j] = ms[j];
  __syncthreads();
  float zs = EF * b1b[j];
  #pragma unroll
  for (int k = 0; k < 32; k++) zs = fmaf(w1b[k * 32 + j], sm[k], zs);
  const float invE = 1.f / EF;
  float mu = zs * invE;
  float var = fmaxf(zq[j] * invE - mu * mu, 0.f);
  float A = g1b[j] * rsqrtf(var + 1e-5f);
  float C = be1b[j] - mu * A;
  float d = (g1b[j] >= 0.f) ? 1.f : -1.f;
  A2d[j] = A * d; C2[j] = C;
  ms[j] = 0.f; zq[j] = 0.f;
}

// BN finalize: a = g*rsqrt(var+eps), c = be - mu*a; zero sums for reuse
__global__ void k_finalize(float* __restrict__ sum, float* __restrict__ ssq,
                           const float* __restrict__ g, const float* __restrict__ be,
                           float inv_n, int ncols, float* __restrict__ a, float* __restrict__ c) {
  int j = threadIdx.x;
  if (j < ncols) {
    float mu = sum[j] * inv_n;
    float var = fmaxf(ssq[j] * inv_n - mu * mu, 0.f);
    float s = rsqrtf(var + 1e-5f) * g[j];
    a[j] = s; c[j] = be[j] - mu * s;
    sum[j] = 0.f; ssq[j] = 0.f;
  }
}

// ---------- agg finalize + h_pre = [x, agg] @ w2a + b2a (+stats) ----------

__global__ __launch_bounds__(256) void k_hpre2(const float* __restrict__ xp,
    const float* __restrict__ tzb, const int* __restrict__ starts,
    const float* __restrict__ A2d, const float* __restrict__ C2, const float* __restrict__ w2aT,
    float* __restrict__ hpre, float* __restrict__ gsum, float* __restrict__ gssq) {
  __shared__ float red[256];
  const int n = blockIdx.x * 256 + threadIdx.x;
  float h[32], hh[32];
  #pragma unroll
  for (int j = 0; j < 32; j++) h[j] = 0.f;
  if (n < NN) {
    float xv[11];
    loadrow(xp, n, xv);
    const int dg = starts[n + 1] - starts[n];
    float av[32];
    if (dg > 0) {
      const float4* tp = reinterpret_cast<const float4*>(tzb + (size_t)n * 32);
      #pragma unroll
      for (int j = 0; j < 8; j++) {
        float4 v = tp[j];
        av[4 * j]     = fmaxf(0.f, fmaf(A2d[4 * j],     v.x, C2[4 * j]));
        av[4 * j + 1] = fmaxf(0.f, fmaf(A2d[4 * j + 1], v.y, C2[4 * j + 1]));
        av[4 * j + 2] = fmaxf(0.f, fmaf(A2d[4 * j + 2], v.z, C2[4 * j + 2]));
        av[4 * j + 3] = fmaxf(0.f, fmaf(A2d[4 * j + 3], v.w, C2[4 * j + 3]));
      }
    } else {
      #pragma unroll
      for (int j = 0; j < 32; j++) av[j] = 0.f;
    }
    #pragma unroll
    for (int j = 0; j < 32; j++) {
      const float* wr = w2aT + j * 44;
      float acc = wr[43];
      #pragma unroll
      for (int k = 0; k < 11; k++) acc = fmaf(xv[k], wr[k], acc);
      #pragma unroll
      for (int k = 0; k < 32; k++) acc = fmaf(av[k], wr[11 + k], acc);
      h[j] = acc;
    }
    float4* hp = reinterpret_cast<float4*>(hpre + (size_t)n * 32);
    #pragma unroll
    for (int j = 0; j < 8; j++)
      hp[j] = make_float4(h[4 * j], h[4 * j + 1], h[4 * j + 2], h[4 * j + 3]);
  }
  #pragma unroll
  for (int j = 0; j < 32; j++) hh[j] = h[j] * h[j];
  reduce64(h, hh, red, gsum, gssq);
}

// comb = relu(relu(bn(h_pre)) @ w2b + b2b) -> xp col 10
__global__ __launch_bounds__(256) void k_comb(const float* __restrict__ hpre,
    const float* __restrict__ a3, const float* __restrict__ c3,
    const float* __restrict__ w2b, const float* __restrict__ b2b, float* __restrict__ xp) {
  const int n = blockIdx.x * 256 + threadIdx.x;
  if (n >= NN) return;
  const float4* hp = reinterpret_cast<const float4*>(hpre + (size_t)n * 32);
  float acc = b2b[0];
  #pragma unroll
  for (int j = 0; j < 8; j++) {
    float4 v = hp[j];
    acc += fmaxf(0.f, fmaf(v.x, a3[4 * j],     c3[4 * j]))     * w2b[4 * j];
    acc += fmaxf(0.f, fmaf(v.y, a3[4 * j + 1], c3[4 * j + 1])) * w2b[4 * j + 1];
    acc += fmaxf(0.f, fmaf(v.z, a3[4 * j + 2], c3[4 * j + 2])) * w2b[4 * j + 2];
    acc += fmaxf(0.f, fmaf(v.w, a3[4 * j + 3], c3[4 * j + 3])) * w2b[4 * j + 3];
  }
  xp[(size_t)n * 12 + 10] = fmaxf(acc, 0.f);
}

// ---------- power MLP ----------

// yp = x @ wpa + bpa : store to ybuf + stats
__global__ __launch_bounds__(256) void k_p5(const float* __restrict__ xp, const float* __restrict__ wpaT,
                                            float* __restrict__ ybuf,
                                            float* __restrict__ gsum, float* __restrict__ gssq) {
  __shared__ float red[256];
  const int n = blockIdx.x * 256 + threadIdx.x;
  float y[32], yy[32];
  #pragma unroll
  for (int j = 0; j < 32; j++) y[j] = 0.f;
  if (n < NN) {
    float xv[11];
    loadrow(xp, n, xv);
    #pragma unroll
    for (int j = 0; j < 32; j++) {
      const float* wr = wpaT + j * 12;
      float acc = wr[11];
      #pragma unroll
      for (int k = 0; k < 11; k++) acc = fmaf(xv[k], wr[k], acc);
      y[j] = acc;
    }
    float4* yp = reinterpret_cast<float4*>(ybuf + (size_t)n * 32);
    #pragma unroll
    for (int j = 0; j < 8; j++)
      yp[j] = make_float4(y[4 * j], y[4 * j + 1], y[4 * j + 2], y[4 * j + 3]);
  }
  #pragma unroll
  for (int j = 0; j < 32; j++) yy[j] = y[j] * y[j];
  reduce64(y, yy, red, gsum, gssq);
}

// yq = relu(bn(yp)) @ wpb + bpb : store + scalar stats (reads stored yp)
__global__ __launch_bounds__(256) void k_p6(const float* __restrict__ ybuf,
    const float* __restrict__ a4, const float* __restrict__ c4,
    const float* __restrict__ wpb, const float* __restrict__ bpb,
    float* __restrict__ yq, float* __restrict__ gsum, float* __restrict__ gssq) {
  __shared__ float red[8];
  const int n = blockIdx.x * 256 + threadIdx.x;
  float sum = 0.f, ssq = 0.f;
  if (n < NN) {
    const float4* yp = reinterpret_cast<const float4*>(ybuf + (size_t)n * 32);
    float q = bpb[0];
    #pragma unroll
    for (int j = 0; j < 8; j++) {
      float4 v = yp[j];
      q = fmaf(fmaxf(0.f, fmaf(v.x, a4[4 * j],     c4[4 * j])),     wpb[4 * j],     q);
      q = fmaf(fmaxf(0.f, fmaf(v.y, a4[4 * j + 1], c4[4 * j + 1])), wpb[4 * j + 1], q);
      q = fmaf(fmaxf(0.f, fmaf(v.z, a4[4 * j + 2], c4[4 * j + 2])), wpb[4 * j + 2], q);
      q = fmaf(fmaxf(0.f, fmaf(v.w, a4[4 * j + 3], c4[4 * j + 3])), wpb[4 * j + 3], q);
    }
    yq[n] = q;
    sum = q; ssq = q * q;
  }
  float s = wsum(sum), qq = wsum(ssq);
  const int wid = threadIdx.x >> 6, lane = threadIdx.x & 63;
  if (lane == 0) { red[wid] = s; red[4 + wid] = qq; }
  __syncthreads();
  if (threadIdx.x == 0) {
    unsafeAtomicAdd(&gsum[0], red[0] + red[1] + red[2] + red[3]);
    unsafeAtomicAdd(&gssq[0], red[4] + red[5] + red[6] + red[7]);
  }
}

__global__ __launch_bounds__(256) void k_p7(const float* __restrict__ yq,
    const float* __restrict__ a5, const float* __restrict__ c5, float* __restrict__ out) {
  int n = blockIdx.x * 256 + threadIdx.x;
  if (n < NN) out[n] = fmaxf(0.f, fmaf(yq[n], a5[0], c5[0]));
}

// ---------- host launch ----------

extern "C" void kernel_launch(void* const* d_in, const int* in_sizes, int n_in,
                              void* d_out, int out_size, void* d_ws, size_t ws_size,
                              hipStream_t stream) {
  const float* x    = (const float*)d_in[0];
  const float* ea   = (const float*)d_in[1];
  const int*   ei   = (const int*)d_in[2];
  const int*   srcp = ei;
  const int*   dstp = ei + EE;
  const float* w1a = (const float*)d_in[3],  *b1a = (const float*)d_in[4];
  const float* g1a = (const float*)d_in[5],  *be1a = (const float*)d_in[6];
  const float* w1b = (const float*)d_in[7],  *b1b = (const float*)d_in[8];
  const float* g1b = (const float*)d_in[9],  *be1b = (const float*)d_in[10];
  const float* w2a = (const float*)d_in[11], *b2a = (const float*)d_in[12];
  const float* g2a = (const float*)d_in[13], *be2a = (const float*)d_in[14];
  const float* w2b = (const float*)d_in[15], *b2b = (const float*)d_in[16];
  const float* wpa = (const float*)d_in[17], *bpa = (const float*)d_in[18];
  const float* gpa = (const float*)d_in[19], *bepa = (const float*)d_in[20];
  const float* wpb = (const float*)d_in[21], *bpb = (const float*)d_in[22];
  const float* gpb = (const float*)d_in[23], *bepb = (const float*)d_in[24];

  size_t off = 0;
  char* base = (char*)d_ws;
  auto alloc = [&](size_t bytes) -> void* {
    void* p = base + off;
    off += (bytes + 255) & ~(size_t)255;
    return p;
  };
  float* stats = (float*)alloc(2048);
  float* coef  = (float*)alloc(2048);
  float* mom   = (float*)alloc(512);
  float* cmom  = (float*)alloc(256);
  float* w1f   = (float*)alloc(16 * 32 * 4);
  float* wexy  = (float*)alloc(64 * 4);
  float* w2tf  = (float*)alloc(32 * 32 * 4);
  float* b1bf  = (float*)alloc(256);
  float* w2aT  = (float*)alloc(32 * 44 * 4);
  float* wpaT  = (float*)alloc(32 * 12 * 4);
  int*   cnt    = (int*)alloc(NN * 4);
  int*   deg    = (int*)alloc(NN * 4);
  float* sea    = (float*)alloc((size_t)NN * 2 * 4);
  int*   starts = (int*)alloc((NN + 1) * 4);
  int*   fill   = (int*)alloc(NN * 4);
  int4*  edg    = (int4*)alloc((size_t)EE * 16);
  float* xp     = (float*)alloc((size_t)NN * 12 * 4);
  float* P      = (float*)alloc((size_t)NN * 32 * 4);
  float* tzb    = (float*)alloc((size_t)NN * 32 * 4);
  float* hpre   = (float*)alloc((size_t)NN * 32 * 4);
  float* yq     = (float*)alloc(NN * 4);

  float *MS2  = stats,       *ZQ2  = stats + 32;
  float *SUM3 = stats + 64,  *SSQ3 = stats + 96;
  float *SUM4 = stats + 128, *SSQ4 = stats + 160;
  float *SUM5 = stats + 192, *SSQ5 = stats + 224;
  float *A2d = coef,       *C2 = coef + 32;
  float *A3  = coef + 64,  *C3 = coef + 96;
  float *A4  = coef + 128, *C4 = coef + 160;
  float *A5  = coef + 192, *C5 = coef + 224;

  hipMemsetAsync(stats, 0, 2048, stream);
  hipMemsetAsync(mom, 0, 512 + 256, stream);   // mom + cmom
  hipMemsetAsync(cnt, 0, NN * 4, stream);
  hipMemsetAsync(deg, 0, NN * 4, stream);
  hipMemsetAsync(sea, 0, (size_t)NN * 2 * 4, stream);

  const int GN = (NN + 255) / 256;          // 391
  const int GW = (NN + 31) / 32;            // 3125 blocks: 32 nodes x 2 parity x 4 channel-slice waves
  const int GE4 = (EE / 4 + 255) / 256;     // 3125

  k_wprep  <<<1, 256, 0, stream>>>(w1b, b1b, g1b, w2a, b2a, wpa, bpa, w2tf, b1bf, w2aT, wpaT);
  k_prep   <<<GE4, 256, 0, stream>>>(dstp, srcp, ea, cnt, deg, sea, cmom);
  k_scan   <<<1, 1024, 0, stream>>>(cnt, starts, fill);
  k_scatter<<<GE4, 256, 0, stream>>>(dstp, srcp, ea, fill, edg);
  k_xp     <<<GN, 256, 0, stream>>>(x, xp);

  const float invN = 1.f / (float)NN;
  for (int c = 0; c < 3; c++) {
    k_mom     <<<GN, 256, 0, stream>>>(xp, deg, sea, mom);
    k_fin1    <<<1, 32, 0, stream>>>(mom, cmom, w1a, b1a, g1a, be1a, w1f, wexy);
    k_P       <<<GN, 256, 0, stream>>>(xp, w1f, P);
    k_fusedagg<<<GW, 256, 0, stream>>>(starts, edg, P, wexy, w2tf, b1bf, tzb, MS2, ZQ2);
    k_fin2    <<<1, 32, 0, stream>>>(MS2, ZQ2, w1b, b1b, g1b, be1b, A2d, C2);
    k_hpre2   <<<GN, 256, 0, stream>>>(xp, tzb, starts, A2d, C2, w2aT, hpre, SUM3, SSQ3);
    k_finalize<<<1, 32, 0, stream>>>(SUM3, SSQ3, g2a, be2a, invN, 32, A3, C3);
    k_comb    <<<GN, 256, 0, stream>>>(hpre, A3, C3, w2b, b2b, xp);
  }

  k_p5      <<<GN, 256, 0, stream>>>(xp, wpaT, hpre, SUM4, SSQ4);
  k_finalize<<<1, 32, 0, stream>>>(SUM4, SSQ4, gpa, bepa, invN, 32, A4, C4);
  k_p6      <<<GN, 256, 0, stream>>>(hpre, A4, C4, wpb, bpb, yq, SUM5, SSQ5);
  k_finalize<<<1, 32, 0, stream>>>(SUM5, SSQ5, gpb, bepb, invN, 1, A5, C5);
  k_p7      <<<GN, 256, 0, stream>>>(yq, A5, C5, (float*)d_out);
}

// Round 7
// 4572.243 us; speedup vs baseline: 1.7419x; 1.7419x over previous
//
#include <hip/hip_runtime.h>
#include <hip/hip_bf16.h>
#include <cstddef>

#define NN 100000
#define EE 3200000
#define NBIN 64
static const float EF = 3200000.0f;

// ---------- helpers ----------

__device__ __forceinline__ float wsum(float v) {
  #pragma unroll
  for (int off = 32; off > 0; off >>= 1) v += __shfl_down(v, off, 64);
  return v;  // lane 0 holds wave total
}

// block-level reduce of 32 sums + 32 sumsq -> global atomics. red = shared float[256].
__device__ __forceinline__ void reduce64(float sum[32], float ssq[32], float* red,
                                         float* __restrict__ gsum, float* __restrict__ gssq) {
  const int wid = threadIdx.x >> 6, lane = threadIdx.x & 63;
  #pragma unroll
  for (int j = 0; j < 32; j++) {
    float a = wsum(sum[j]);
    float b = wsum(ssq[j]);
    if (lane == 0) { red[wid * 64 + j] = a; red[wid * 64 + 32 + j] = b; }
  }
  __syncthreads();
  if (threadIdx.x < 64) {
    float t = red[threadIdx.x] + red[64 + threadIdx.x] + red[128 + threadIdx.x] + red[192 + threadIdx.x];
    if (threadIdx.x < 32) unsafeAtomicAdd(&gsum[threadIdx.x], t);
    else                  unsafeAtomicAdd(&gssq[threadIdx.x - 32], t);
  }
}

__device__ __forceinline__ void loadrow(const float* __restrict__ xp, int s, float in[13]) {
  const float4* xr = reinterpret_cast<const float4*>(xp + (size_t)s * 12);
  float4 r0 = xr[0], r1 = xr[1], r2 = xr[2];
  in[0]=r0.x; in[1]=r0.y; in[2]=r0.z; in[3]=r0.w; in[4]=r1.x; in[5]=r1.y; in[6]=r1.z; in[7]=r1.w;
  in[8]=r2.x; in[9]=r2.y; in[10]=r2.z;
}

// ---------- setup kernels ----------

// w2tf[j][k] = d_j * w1b[k][j] (d_j = sign(g1b_j)); b1bf[j] = d_j*b1b[j];
// w2aT[j][0..42]+bias at 43; wpaT[j][0..10]+bias at 11
__global__ __launch_bounds__(256) void k_wprep(const float* __restrict__ w1b,
    const float* __restrict__ b1b, const float* __restrict__ g1b,
    const float* __restrict__ w2a, const float* __restrict__ b2a,
    const float* __restrict__ wpa, const float* __restrict__ bpa,
    float* __restrict__ w2tf, float* __restrict__ b1bf,
    float* __restrict__ w2aT, float* __restrict__ wpaT) {
  int t = threadIdx.x;
  for (int i = t; i < 1024; i += 256) {
    int j = i >> 5, k = i & 31;
    float d = (g1b[j] >= 0.f) ? 1.f : -1.f;
    w2tf[j * 32 + k] = d * w1b[k * 32 + j];
  }
  for (int i = t; i < 32 * 43; i += 256) { int j = i & 31, k = i >> 5; w2aT[j * 44 + k] = w2a[k * 32 + j]; }
  for (int i = t; i < 32 * 11; i += 256) { int j = i & 31, k = i >> 5; wpaT[j * 12 + k] = wpa[k * 32 + j]; }
  if (t < 32) {
    float d = (g1b[t] >= 0.f) ? 1.f : -1.f;
    b1bf[t] = d * b1b[t];
    w2aT[t * 44 + 43] = b2a[t];
    wpaT[t * 12 + 11] = bpa[t];
  }
}

// one edge pass (4 edges/thread/iter): dst counts, src out-degrees, per-src ea sums, global ea moments
__global__ __launch_bounds__(256) void k_prep(const int* __restrict__ dst, const int* __restrict__ src,
    const float* __restrict__ ea, int* __restrict__ cnt, int* __restrict__ deg,
    float* __restrict__ sea, float* __restrict__ cmom) {
  float p0 = 0, p1 = 0, p2 = 0, p3 = 0, p4 = 0;
  const int S = gridDim.x * 256;
  for (int g = blockIdx.x * 256 + threadIdx.x; g < EE / 4; g += S) {
    int4 d4 = reinterpret_cast<const int4*>(dst)[g];
    int4 s4 = reinterpret_cast<const int4*>(src)[g];
    float4 e0 = reinterpret_cast<const float4*>(ea)[2 * g];
    float4 e1 = reinterpret_cast<const float4*>(ea)[2 * g + 1];
    atomicAdd(&cnt[d4.x], 1); atomicAdd(&cnt[d4.y], 1); atomicAdd(&cnt[d4.z], 1); atomicAdd(&cnt[d4.w], 1);
    atomicAdd(&deg[s4.x], 1); atomicAdd(&deg[s4.y], 1); atomicAdd(&deg[s4.z], 1); atomicAdd(&deg[s4.w], 1);
    unsafeAtomicAdd(&sea[2 * s4.x], e0.x); unsafeAtomicAdd(&sea[2 * s4.x + 1], e0.y);
    unsafeAtomicAdd(&sea[2 * s4.y], e0.z); unsafeAtomicAdd(&sea[2 * s4.y + 1], e0.w);
    unsafeAtomicAdd(&sea[2 * s4.z], e1.x); unsafeAtomicAdd(&sea[2 * s4.z + 1], e1.y);
    unsafeAtomicAdd(&sea[2 * s4.w], e1.z); unsafeAtomicAdd(&sea[2 * s4.w + 1], e1.w);
    p0 += e0.x * e0.x + e0.z * e0.z + e1.x * e1.x + e1.z * e1.z;
    p1 += e0.x * e0.y + e0.z * e0.w + e1.x * e1.y + e1.z * e1.w;
    p2 += e0.y * e0.y + e0.w * e0.w + e1.y * e1.y + e1.w * e1.w;
    p3 += e0.x + e0.z + e1.x + e1.z;
    p4 += e0.y + e0.w + e1.y + e1.w;
  }
  p0 = wsum(p0); p1 = wsum(p1); p2 = wsum(p2); p3 = wsum(p3); p4 = wsum(p4);
  if ((threadIdx.x & 63) == 0) {
    unsafeAtomicAdd(&cmom[0], p0); unsafeAtomicAdd(&cmom[1], p1); unsafeAtomicAdd(&cmom[2], p2);
    unsafeAtomicAdd(&cmom[3], p3); unsafeAtomicAdd(&cmom[4], p4);
  }
}

__global__ __launch_bounds__(1024) void k_scan(const int* __restrict__ cnt,
                                               int* __restrict__ starts, int* __restrict__ fill) {
  __shared__ int part[1024];
  const int T = 1024, CH = (NN + T - 1) / T;
  int t = threadIdx.x;
  int lo = t * CH, hi = min(lo + CH, NN);
  int s = 0;
  for (int i = lo; i < hi; i++) s += cnt[i];
  part[t] = s; __syncthreads();
  for (int off = 1; off < T; off <<= 1) {
    int v = (t >= off) ? part[t - off] : 0;
    __syncthreads();
    part[t] += v;
    __syncthreads();
  }
  int run = part[t] - s;  // exclusive prefix
  for (int i = lo; i < hi; i++) { starts[i] = run; fill[i] = run; run += cnt[i]; }
  if (t == T - 1) starts[NN] = EE;
}

// scatter packed 16B edge records (src, ea.x, ea.y, 0) into CSR order
__global__ __launch_bounds__(256) void k_scatter(const int* __restrict__ dst, const int* __restrict__ src,
    const float* __restrict__ ea, int* __restrict__ fill, int4* __restrict__ edg) {
  const int S = gridDim.x * 256;
  for (int g = blockIdx.x * 256 + threadIdx.x; g < EE / 4; g += S) {
    int4 d4 = reinterpret_cast<const int4*>(dst)[g];
    int4 s4 = reinterpret_cast<const int4*>(src)[g];
    float4 e0 = reinterpret_cast<const float4*>(ea)[2 * g];
    float4 e1 = reinterpret_cast<const float4*>(ea)[2 * g + 1];
    int p0 = atomicAdd(&fill[d4.x], 1);
    edg[p0] = make_int4(s4.x, __float_as_int(e0.x), __float_as_int(e0.y), 0);
    int p1 = atomicAdd(&fill[d4.y], 1);
    edg[p1] = make_int4(s4.y, __float_as_int(e0.z), __float_as_int(e0.w), 0);
    int p2 = atomicAdd(&fill[d4.z], 1);
    edg[p2] = make_int4(s4.z, __float_as_int(e1.x), __float_as_int(e1.y), 0);
    int p3 = atomicAdd(&fill[d4.w], 1);
    edg[p3] = make_int4(s4.w, __float_as_int(e1.z), __float_as_int(e1.w), 0);
  }
}

// padded node rows: xp[n][0..9]=x cols 0..9, [10]=x col10 (current), [11]=0
__global__ __launch_bounds__(256) void k_xp(const float* __restrict__ x, float* __restrict__ xp) {
  int n = blockIdx.x * 256 + threadIdx.x;
  if (n >= NN) return;
  float v[11];
  #pragma unroll
  for (int k = 0; k < 11; k++) v[k] = x[(size_t)n * 11 + k];
  float4* o = reinterpret_cast<float4*>(xp + (size_t)n * 12);
  o[0] = make_float4(v[0], v[1], v[2], v[3]);
  o[1] = make_float4(v[4], v[5], v[6], v[7]);
  o[2] = make_float4(v[8], v[9], v[10], 0.f);
}

// ---------- per-conv: input moments (node pass) ----------
// mom layout: [0..10]=S_x (deg-weighted), [11..76]=sxx upper-tri(11), [77..98]=sxe
__global__ __launch_bounds__(256) void k_mom(const float* __restrict__ xp, const int* __restrict__ deg,
                                             const float* __restrict__ sea, float* __restrict__ mom) {
  const int n = blockIdx.x * 256 + threadIdx.x;
  const int lane = threadIdx.x & 63;
  float v[11]; float w = 0.f; float sx = 0.f, sy = 0.f;
  #pragma unroll
  for (int k = 0; k < 11; k++) v[k] = 0.f;
  if (n < NN) {
    w = (float)deg[n];
    loadrow(xp, n, v);
    sx = sea[2 * n]; sy = sea[2 * n + 1];
  }
  int ch = 0;
  #pragma unroll
  for (int a = 0; a < 11; a++) {
    float r = wsum(w * v[a]);
    if (lane == 0) unsafeAtomicAdd(&mom[ch], r);
    ch++;
  }
  #pragma unroll
  for (int a = 0; a < 11; a++) {
    #pragma unroll
    for (int b = a; b < 11; b++) {
      float r = wsum(w * v[a] * v[b]);
      if (lane == 0) unsafeAtomicAdd(&mom[ch], r);
      ch++;
    }
  }
  #pragma unroll
  for (int a = 0; a < 11; a++) {
    float rx = wsum(v[a] * sx);
    if (lane == 0) unsafeAtomicAdd(&mom[ch], rx);
    ch++;
    float ry = wsum(v[a] * sy);
    if (lane == 0) unsafeAtomicAdd(&mom[ch], ry);
    ch++;
  }
}

__device__ __forceinline__ float msym(const float* mom, const float* cmom, int k, int l) {
  int a = min(k, l), b = max(k, l);
  if (b < 11) return mom[11 + a * 11 - a * (a - 1) / 2 + (b - a)];
  if (a < 11) return mom[77 + a * 2 + (b - 11)];
  return cmom[(a - 11) + (b - 11)];
}

// layer-1 BN params from moments; emit FOLDED transposed weights w1f[j][0..12]+bias[13]
// plus compact edge-attr weight arrays wexy[0..31]=A*w[11], wexy[32..63]=A*w[12]; zero mom.
__global__ void k_fin1(float* __restrict__ mom, const float* __restrict__ cmom,
    const float* __restrict__ w1a, const float* __restrict__ b1a,
    const float* __restrict__ g1a, const float* __restrict__ be1a,
    float* __restrict__ w1f, float* __restrict__ wexy) {
  int j = threadIdx.x;  // 32 threads
  float w[13], S[13];
  #pragma unroll
  for (int k = 0; k < 13; k++) w[k] = w1a[k * 32 + j];
  #pragma unroll
  for (int k = 0; k < 11; k++) S[k] = mom[k];
  S[11] = cmom[3]; S[12] = cmom[4];
  float lin = 0.f;
  #pragma unroll
  for (int k = 0; k < 13; k++) lin = fmaf(w[k], S[k], lin);
  float quad = 0.f;
  #pragma unroll
  for (int k = 0; k < 13; k++)
    #pragma unroll
    for (int l = 0; l < 13; l++) quad = fmaf(w[k] * w[l], msym(mom, cmom, k, l), quad);
  const float invE = 1.f / EF;
  float b = b1a[j];
  float mean = fmaf(lin, invE, b);
  float ey2 = (quad + 2.f * b * lin) * invE + b * b;
  float var = fmaxf(ey2 - mean * mean, 0.f);
  float A = g1a[j] * rsqrtf(var + 1e-5f);
  float C = be1a[j] - mean * A;
  #pragma unroll
  for (int k = 0; k < 13; k++) w1f[j * 16 + k] = A * w[k];
  w1f[j * 16 + 13] = fmaf(A, b, C);
  w1f[j * 16 + 14] = 0.f; w1f[j * 16 + 15] = 0.f;
  wexy[j] = A * w[11];
  wexy[32 + j] = A * w[12];
  __syncthreads();
  for (int i = j; i < 128; i += 32) mom[i] = 0.f;
}

// P[n][32] = folded layer-1 pre-activation from node features only (edge attrs added per edge)
__global__ __launch_bounds__(256) void k_P(const float* __restrict__ xp, const float* __restrict__ w1f,
                                           float* __restrict__ P) {
  const int n = blockIdx.x * 256 + threadIdx.x;
  if (n >= NN) return;
  float xv[11];
  loadrow(xp, n, xv);
  float4* op = reinterpret_cast<float4*>(P + (size_t)n * 32);
  #pragma unroll
  for (int jj = 0; jj < 8; jj++) {
    float o[4];
    #pragma unroll
    for (int u = 0; u < 4; u++) {
      int j = 4 * jj + u;
      const float* wr = w1f + j * 16;
      float acc = wr[13];
      #pragma unroll
      for (int k = 0; k < 11; k++) acc = fmaf(xv[k], wr[k], acc);
      o[u] = acc;
    }
    op[jj] = make_float4(o[0], o[1], o[2], o[3]);
  }
}

// ---------- fused edge pass: lane = channel, weights register-resident ----------
// Each 32-lane half-wave owns ONE node; lane j owns channel j and holds W column j
// (= w2tf row j, 32 floats) in VGPRs, loaded once. Per edge: lane j computes m_j,
// the 32 m's are exchanged via a 128B LDS slot (1 ds_write + 8 broadcast b128 reads),
// then z_j = 32 register FMAs. Per-channel stats are lane-local scalars.
__global__ __launch_bounds__(256, 6) void k_fusedagg(
    const int* __restrict__ starts, const int4* __restrict__ edg,
    const float* __restrict__ P, const float* __restrict__ wexy,
    const float* __restrict__ w2tf, const float* __restrict__ b1bf,
    float* __restrict__ tzb, float* __restrict__ gms, float* __restrict__ gzq) {
  __shared__ float smx[4][2][32];
  __shared__ float redm[4][32], redq[4][32];
  const int tid = threadIdx.x;
  const int wid = tid >> 6, lane = tid & 63;
  const int half = lane >> 5, j = lane & 31;
  const int n = blockIdx.x * 8 + wid * 2 + half;   // NN = 12500*8 exactly
  // per-lane channel constants (loaded once; coalesced)
  const float wex = wexy[j], wey = wexy[32 + j], bz = b1bf[j];
  const float4* wc = reinterpret_cast<const float4*>(w2tf + (size_t)j * 32);
  const float4 wv0 = wc[0], wv1 = wc[1], wv2 = wc[2], wv3 = wc[3];
  const float4 wv4 = wc[4], wv5 = wc[5], wv6 = wc[6], wv7 = wc[7];
  float tz = -3.0e38f, zq = 0.f, ms = 0.f;
  int lo = 0, hi = 0;
  if (n < NN) { lo = starts[n]; hi = starts[n + 1]; }
  float* msl = &smx[wid][half][0];
  int sl = lo;
  int4 eA = make_int4(0, 0, 0, 0), eB = make_int4(0, 0, 0, 0);
  float pA = 0.f;
  if (sl < hi) {
    eA = edg[sl];
    pA = P[(size_t)eA.x * 32 + j];
  }
  if (sl + 1 < hi) eB = edg[sl + 1];
  while (sl < hi) {
    // prefetch (independent of current compute): edge i+2 record, edge i+1 P value
    int4 eC = eB;
    if (sl + 2 < hi) eC = edg[sl + 2];
    float pN = pA;
    if (sl + 1 < hi) pN = P[(size_t)eB.x * 32 + j];
    // current edge
    const float ex = __int_as_float(eA.y), ey = __int_as_float(eA.z);
    const float m = fmaxf(0.f, fmaf(ex, wex, fmaf(ey, wey, pA)));
    ms += m;
    msl[j] = m;
    __builtin_amdgcn_wave_barrier();
    const float4 m0 = *reinterpret_cast<const float4*>(msl + 0);
    const float4 m1 = *reinterpret_cast<const float4*>(msl + 4);
    const float4 m2 = *reinterpret_cast<const float4*>(msl + 8);
    const float4 m3 = *reinterpret_cast<const float4*>(msl + 12);
    const float4 m4 = *reinterpret_cast<const float4*>(msl + 16);
    const float4 m5 = *reinterpret_cast<const float4*>(msl + 20);
    const float4 m6 = *reinterpret_cast<const float4*>(msl + 24);
    const float4 m7 = *reinterpret_cast<const float4*>(msl + 28);
    __builtin_amdgcn_wave_barrier();
    float z0 = bz, z1 = 0.f, z2 = 0.f, z3 = 0.f;
    z0 = fmaf(m0.x, wv0.x, z0); z1 = fmaf(m0.y, wv0.y, z1);
    z2 = fmaf(m0.z, wv0.z, z2); z3 = fmaf(m0.w, wv0.w, z3);
    z0 = fmaf(m1.x, wv1.x, z0); z1 = fmaf(m1.y, wv1.y, z1);
    z2 = fmaf(m1.z, wv1.z, z2); z3 = fmaf(m1.w, wv1.w, z3);
    z0 = fmaf(m2.x, wv2.x, z0); z1 = fmaf(m2.y, wv2.y, z1);
    z2 = fmaf(m2.z, wv2.z, z2); z3 = fmaf(m2.w, wv2.w, z3);
    z0 = fmaf(m3.x, wv3.x, z0); z1 = fmaf(m3.y, wv3.y, z1);
    z2 = fmaf(m3.z, wv3.z, z2); z3 = fmaf(m3.w, wv3.w, z3);
    z0 = fmaf(m4.x, wv4.x, z0); z1 = fmaf(m4.y, wv4.y, z1);
    z2 = fmaf(m4.z, wv4.z, z2); z3 = fmaf(m4.w, wv4.w, z3);
    z0 = fmaf(m5.x, wv5.x, z0); z1 = fmaf(m5.y, wv5.y, z1);
    z2 = fmaf(m5.z, wv5.z, z2); z3 = fmaf(m5.w, wv5.w, z3);
    z0 = fmaf(m6.x, wv6.x, z0); z1 = fmaf(m6.y, wv6.y, z1);
    z2 = fmaf(m6.z, wv6.z, z2); z3 = fmaf(m6.w, wv6.w, z3);
    z0 = fmaf(m7.x, wv7.x, z0); z1 = fmaf(m7.y, wv7.y, z1);
    z2 = fmaf(m7.z, wv7.z, z2); z3 = fmaf(m7.w, wv7.w, z3);
    const float z = (z0 + z1) + (z2 + z3);
    tz = fmaxf(tz, z);
    zq = fmaf(z, z, zq);
    // rotate pipeline
    eA = eB; eB = eC; pA = pN;
    ++sl;
  }
  // write per-node channel max (lane j -> tzb[n*32+j], coalesced per half)
  if (n < NN) tzb[(size_t)n * 32 + j] = tz;
  // stats: combine halves (same channel j), then block-reduce, then binned atomics
  float msT = ms + __shfl_xor(ms, 32, 64);
  float zqT = zq + __shfl_xor(zq, 32, 64);
  if (lane < 32) { redm[wid][j] = msT; redq[wid][j] = zqT; }
  __syncthreads();
  if (tid < 32) {
    float a = redm[0][tid] + redm[1][tid] + redm[2][tid] + redm[3][tid];
    float b = redq[0][tid] + redq[1][tid] + redq[2][tid] + redq[3][tid];
    const int bin = blockIdx.x & (NBIN - 1);
    unsafeAtomicAdd(&gms[bin * 32 + tid], a);
    unsafeAtomicAdd(&gzq[bin * 32 + tid], b);
  }
}

// layer-2 BN from binned stats: zs_j = w1b[:,j]·ms + E*b1b_j; A2d = A2*sign(g1b); zero bins
__global__ void k_fin2(float* __restrict__ gms, float* __restrict__ gzq,
    const float* __restrict__ w1b, const float* __restrict__ b1b,
    const float* __restrict__ g1b, const float* __restrict__ be1b,
    float* __restrict__ A2d, float* __restrict__ C2) {
  __shared__ float sm[32];
  int j = threadIdx.x;  // 32 threads
  float msj = 0.f, zqj = 0.f;
  for (int b = 0; b < NBIN; b++) { msj += gms[b * 32 + j]; zqj += gzq[b * 32 + j]; }
  sm[j] = msj;
  __syncthreads();
  float zs = EF * b1b[j];
  #pragma unroll
  for (int k = 0; k < 32; k++) zs = fmaf(w1b[k * 32 + j], sm[k], zs);
  const float invE = 1.f / EF;
  float mu = zs * invE;
  float var = fmaxf(zqj * invE - mu * mu, 0.f);
  float A = g1b[j] * rsqrtf(var + 1e-5f);
  float C = be1b[j] - mu * A;
  float d = (g1b[j] >= 0.f) ? 1.f : -1.f;
  A2d[j] = A * d; C2[j] = C;
  for (int b = 0; b < NBIN; b++) { gms[b * 32 + j] = 0.f; gzq[b * 32 + j] = 0.f; }
}

// BN finalize: a = g*rsqrt(var+eps), c = be - mu*a; zero sums for reuse
__global__ void k_finalize(float* __restrict__ sum, float* __restrict__ ssq,
                           const float* __restrict__ g, const float* __restrict__ be,
                           float inv_n, int ncols, float* __restrict__ a, float* __restrict__ c) {
  int j = threadIdx.x;
  if (j < ncols) {
    float mu = sum[j] * inv_n;
    float var = fmaxf(ssq[j] * inv_n - mu * mu, 0.f);
    float s = rsqrtf(var + 1e-5f) * g[j];
    a[j] = s; c[j] = be[j] - mu * s;
    sum[j] = 0.f; ssq[j] = 0.f;
  }
}

// ---------- agg finalize + h_pre = [x, agg] @ w2a + b2a (+stats) ----------

__global__ __launch_bounds__(256) void k_hpre2(const float* __restrict__ xp,
    const float* __restrict__ tzb, const int* __restrict__ starts,
    const float* __restrict__ A2d, const float* __restrict__ C2, const float* __restrict__ w2aT,
    float* __restrict__ hpre, float* __restrict__ gsum, float* __restrict__ gssq) {
  __shared__ float red[256];
  const int n = blockIdx.x * 256 + threadIdx.x;
  float h[32], hh[32];
  #pragma unroll
  for (int j = 0; j < 32; j++) h[j] = 0.f;
  if (n < NN) {
    float xv[11];
    loadrow(xp, n, xv);
    const int dg = starts[n + 1] - starts[n];
    float av[32];
    if (dg > 0) {
      const float4* tp = reinterpret_cast<const float4*>(tzb + (size_t)n * 32);
      #pragma unroll
      for (int j = 0; j < 8; j++) {
        float4 v = tp[j];
        av[4 * j]     = fmaxf(0.f, fmaf(A2d[4 * j],     v.x, C2[4 * j]));
        av[4 * j + 1] = fmaxf(0.f, fmaf(A2d[4 * j + 1], v.y, C2[4 * j + 1]));
        av[4 * j + 2] = fmaxf(0.f, fmaf(A2d[4 * j + 2], v.z, C2[4 * j + 2]));
        av[4 * j + 3] = fmaxf(0.f, fmaf(A2d[4 * j + 3], v.w, C2[4 * j + 3]));
      }
    } else {
      #pragma unroll
      for (int j = 0; j < 32; j++) av[j] = 0.f;
    }
    #pragma unroll
    for (int j = 0; j < 32; j++) {
      const float* wr = w2aT + j * 44;
      float acc = wr[43];
      #pragma unroll
      for (int k = 0; k < 11; k++) acc = fmaf(xv[k], wr[k], acc);
      #pragma unroll
      for (int k = 0; k < 32; k++) acc = fmaf(av[k], wr[11 + k], acc);
      h[j] = acc;
    }
    float4* hp = reinterpret_cast<float4*>(hpre + (size_t)n * 32);
    #pragma unroll
    for (int j = 0; j < 8; j++)
      hp[j] = make_float4(h[4 * j], h[4 * j + 1], h[4 * j + 2], h[4 * j + 3]);
  }
  #pragma unroll
  for (int j = 0; j < 32; j++) hh[j] = h[j] * h[j];
  reduce64(h, hh, red, gsum, gssq);
}

// comb = relu(relu(bn(h_pre)) @ w2b + b2b) -> xp col 10
__global__ __launch_bounds__(256) void k_comb(const float* __restrict__ hpre,
    const float* __restrict__ a3, const float* __restrict__ c3,
    const float* __restrict__ w2b, const float* __restrict__ b2b, float* __restrict__ xp) {
  const int n = blockIdx.x * 256 + threadIdx.x;
  if (n >= NN) return;
  const float4* hp = reinterpret_cast<const float4*>(hpre + (size_t)n * 32);
  float acc = b2b[0];
  #pragma unroll
  for (int j = 0; j < 8; j++) {
    float4 v = hp[j];
    acc += fmaxf(0.f, fmaf(v.x, a3[4 * j],     c3[4 * j]))     * w2b[4 * j];
    acc += fmaxf(0.f, fmaf(v.y, a3[4 * j + 1], c3[4 * j + 1])) * w2b[4 * j + 1];
    acc += fmaxf(0.f, fmaf(v.z, a3[4 * j + 2], c3[4 * j + 2])) * w2b[4 * j + 2];
    acc += fmaxf(0.f, fmaf(v.w, a3[4 * j + 3], c3[4 * j + 3])) * w2b[4 * j + 3];
  }
  xp[(size_t)n * 12 + 10] = fmaxf(acc, 0.f);
}

// ---------- power MLP ----------

// yp = x @ wpa + bpa : store to ybuf + stats
__global__ __launch_bounds__(256) void k_p5(const float* __restrict__ xp, const float* __restrict__ wpaT,
                                            float* __restrict__ ybuf,
                                            float* __restrict__ gsum, float* __restrict__ gssq) {
  __shared__ float red[256];
  const int n = blockIdx.x * 256 + threadIdx.x;
  float y[32], yy[32];
  #pragma unroll
  for (int j = 0; j < 32; j++) y[j] = 0.f;
  if (n < NN) {
    float xv[11];
    loadrow(xp, n, xv);
    #pragma unroll
    for (int j = 0; j < 32; j++) {
      const float* wr = wpaT + j * 12;
      float acc = wr[11];
      #pragma unroll
      for (int k = 0; k < 11; k++) acc = fmaf(xv[k], wr[k], acc);
      y[j] = acc;
    }
    float4* yp = reinterpret_cast<float4*>(ybuf + (size_t)n * 32);
    #pragma unroll
    for (int j = 0; j < 8; j++)
      yp[j] = make_float4(y[4 * j], y[4 * j + 1], y[4 * j + 2], y[4 * j + 3]);
  }
  #pragma unroll
  for (int j = 0; j < 32; j++) yy[j] = y[j] * y[j];
  reduce64(y, yy, red, gsum, gssq);
}

// yq = relu(bn(yp)) @ wpb + bpb : store + scalar stats (reads stored yp)
__global__ __launch_bounds__(256) void k_p6(const float* __restrict__ ybuf,
    const float* __restrict__ a4, const float* __restrict__ c4,
    const float* __restrict__ wpb, const float* __restrict__ bpb,
    float* __restrict__ yq, float* __restrict__ gsum, float* __restrict__ gssq) {
  __shared__ float red[8];
  const int n = blockIdx.x * 256 + threadIdx.x;
  float sum = 0.f, ssq = 0.f;
  if (n < NN) {
    const float4* yp = reinterpret_cast<const float4*>(ybuf + (size_t)n * 32);
    float q = bpb[0];
    #pragma unroll
    for (int j = 0; j < 8; j++) {
      float4 v = yp[j];
      q = fmaf(fmaxf(0.f, fmaf(v.x, a4[4 * j],     c4[4 * j])),     wpb[4 * j],     q);
      q = fmaf(fmaxf(0.f, fmaf(v.y, a4[4 * j + 1], c4[4 * j + 1])), wpb[4 * j + 1], q);
      q = fmaf(fmaxf(0.f, fmaf(v.z, a4[4 * j + 2], c4[4 * j + 2])), wpb[4 * j + 2], q);
      q = fmaf(fmaxf(0.f, fmaf(v.w, a4[4 * j + 3], c4[4 * j + 3])), wpb[4 * j + 3], q);
    }
    yq[n] = q;
    sum = q; ssq = q * q;
  }
  float s = wsum(sum), qq = wsum(ssq);
  const int wid = threadIdx.x >> 6, lane = threadIdx.x & 63;
  if (lane == 0) { red[wid] = s; red[4 + wid] = qq; }
  __syncthreads();
  if (threadIdx.x == 0) {
    unsafeAtomicAdd(&gsum[0], red[0] + red[1] + red[2] + red[3]);
    unsafeAtomicAdd(&gssq[0], red[4] + red[5] + red[6] + red[7]);
  }
}

__global__ __launch_bounds__(256) void k_p7(const float* __restrict__ yq,
    const float* __restrict__ a5, const float* __restrict__ c5, float* __restrict__ out) {
  int n = blockIdx.x * 256 + threadIdx.x;
  if (n < NN) out[n] = fmaxf(0.f, fmaf(yq[n], a5[0], c5[0]));
}

// ---------- host launch ----------

extern "C" void kernel_launch(void* const* d_in, const int* in_sizes, int n_in,
                              void* d_out, int out_size, void* d_ws, size_t ws_size,
                              hipStream_t stream) {
  const float* x    = (const float*)d_in[0];
  const float* ea   = (const float*)d_in[1];
  const int*   ei   = (const int*)d_in[2];
  const int*   srcp = ei;
  const int*   dstp = ei + EE;
  const float* w1a = (const float*)d_in[3],  *b1a = (const float*)d_in[4];
  const float* g1a = (const float*)d_in[5],  *be1a = (const float*)d_in[6];
  const float* w1b = (const float*)d_in[7],  *b1b = (const float*)d_in[8];
  const float* g1b = (const float*)d_in[9],  *be1b = (const float*)d_in[10];
  const float* w2a = (const float*)d_in[11], *b2a = (const float*)d_in[12];
  const float* g2a = (const float*)d_in[13], *be2a = (const float*)d_in[14];
  const float* w2b = (const float*)d_in[15], *b2b = (const float*)d_in[16];
  const float* wpa = (const float*)d_in[17], *bpa = (const float*)d_in[18];
  const float* gpa = (const float*)d_in[19], *bepa = (const float*)d_in[20];
  const float* wpb = (const float*)d_in[21], *bpb = (const float*)d_in[22];
  const float* gpb = (const float*)d_in[23], *bepb = (const float*)d_in[24];

  size_t off = 0;
  char* base = (char*)d_ws;
  auto alloc = [&](size_t bytes) -> void* {
    void* p = base + off;
    off += (bytes + 255) & ~(size_t)255;
    return p;
  };
  float* stats = (float*)alloc(2048);
  float* coef  = (float*)alloc(2048);
  float* mom   = (float*)alloc(512);
  float* cmom  = (float*)alloc(256);
  float* gmsB  = (float*)alloc(NBIN * 32 * 4);
  float* gzqB  = (float*)alloc(NBIN * 32 * 4);
  float* w1f   = (float*)alloc(16 * 32 * 4);
  float* wexy  = (float*)alloc(64 * 4);
  float* w2tf  = (float*)alloc(32 * 32 * 4);
  float* b1bf  = (float*)alloc(256);
  float* w2aT  = (float*)alloc(32 * 44 * 4);
  float* wpaT  = (float*)alloc(32 * 12 * 4);
  int*   cnt    = (int*)alloc(NN * 4);
  int*   deg    = (int*)alloc(NN * 4);
  float* sea    = (float*)alloc((size_t)NN * 2 * 4);
  int*   starts = (int*)alloc((NN + 1) * 4);
  int*   fill   = (int*)alloc(NN * 4);
  int4*  edg    = (int4*)alloc((size_t)EE * 16);
  float* xp     = (float*)alloc((size_t)NN * 12 * 4);
  float* P      = (float*)alloc((size_t)NN * 32 * 4);
  float* tzb    = (float*)alloc((size_t)NN * 32 * 4);
  float* hpre   = (float*)alloc((size_t)NN * 32 * 4);
  float* yq     = (float*)alloc(NN * 4);

  float *SUM3 = stats + 64,  *SSQ3 = stats + 96;
  float *SUM4 = stats + 128, *SSQ4 = stats + 160;
  float *SUM5 = stats + 192, *SSQ5 = stats + 224;
  float *A2d = coef,       *C2 = coef + 32;
  float *A3  = coef + 64,  *C3 = coef + 96;
  float *A4  = coef + 128, *C4 = coef + 160;
  float *A5  = coef + 192, *C5 = coef + 224;

  hipMemsetAsync(stats, 0, 2048, stream);
  hipMemsetAsync(mom, 0, 512 + 256, stream);               // mom + cmom (contiguous)
  hipMemsetAsync(gmsB, 0, NBIN * 32 * 4 * 2, stream);      // gmsB + gzqB (contiguous)
  hipMemsetAsync(cnt, 0, NN * 4, stream);
  hipMemsetAsync(deg, 0, NN * 4, stream);
  hipMemsetAsync(sea, 0, (size_t)NN * 2 * 4, stream);

  const int GN = (NN + 255) / 256;          // 391
  const int GW = NN / 8;                    // 12500 blocks: 8 nodes x (4 waves x 2 halves)
  const int GE4 = (EE / 4 + 255) / 256;     // 3125

  k_wprep  <<<1, 256, 0, stream>>>(w1b, b1b, g1b, w2a, b2a, wpa, bpa, w2tf, b1bf, w2aT, wpaT);
  k_prep   <<<GE4, 256, 0, stream>>>(dstp, srcp, ea, cnt, deg, sea, cmom);
  k_scan   <<<1, 1024, 0, stream>>>(cnt, starts, fill);
  k_scatter<<<GE4, 256, 0, stream>>>(dstp, srcp, ea, fill, edg);
  k_xp     <<<GN, 256, 0, stream>>>(x, xp);

  const float invN = 1.f / (float)NN;
  for (int c = 0; c < 3; c++) {
    k_mom     <<<GN, 256, 0, stream>>>(xp, deg, sea, mom);
    k_fin1    <<<1, 32, 0, stream>>>(mom, cmom, w1a, b1a, g1a, be1a, w1f, wexy);
    k_P       <<<GN, 256, 0, stream>>>(xp, w1f, P);
    k_fusedagg<<<GW, 256, 0, stream>>>(starts, edg, P, wexy, w2tf, b1bf, tzb, gmsB, gzqB);
    k_fin2    <<<1, 32, 0, stream>>>(gmsB, gzqB, w1b, b1b, g1b, be1b, A2d, C2);
    k_hpre2   <<<GN, 256, 0, stream>>>(xp, tzb, starts, A2d, C2, w2aT, hpre, SUM3, SSQ3);
    k_finalize<<<1, 32, 0, stream>>>(SUM3, SSQ3, g2a, be2a, invN, 32, A3, C3);
    k_comb    <<<GN, 256, 0, stream>>>(hpre, A3, C3, w2b, b2b, xp);
  }

  k_p5      <<<GN, 256, 0, stream>>>(xp, wpaT, hpre, SUM4, SSQ4);
  k_finalize<<<1, 32, 0, stream>>>(SUM4, SSQ4, gpa, bepa, invN, 32, A4, C4);
  k_p6      <<<GN, 256, 0, stream>>>(hpre, A4, C4, wpb, bpb, yq, SUM5, SSQ5);
  k_finalize<<<1, 32, 0, stream>>>(SUM5, SSQ5, gpb, bepb, invN, 1, A5, C5);
  k_p7      <<<GN, 256, 0, stream>>>(yq, A5, C5, (float*)d_out);
}

// Round 8
// 4214.735 us; speedup vs baseline: 1.8896x; 1.0848x over previous
//
#include <hip/hip_runtime.h>
#include <hip/hip_bf16.h>
#include <cstddef>

#define NN 100000
#define EE 3200000
#define NBIN 64
static const float EF = 3200000.0f;

// ---------- helpers ----------

__device__ __forceinline__ float wsum(float v) {
  #pragma unroll
  for (int off = 32; off > 0; off >>= 1) v += __shfl_down(v, off, 64);
  return v;  // lane 0 holds wave total
}

// block-level reduce of 32 sums + 32 sumsq -> global atomics. red = shared float[256].
__device__ __forceinline__ void reduce64(float sum[32], float ssq[32], float* red,
                                         float* __restrict__ gsum, float* __restrict__ gssq) {
  const int wid = threadIdx.x >> 6, lane = threadIdx.x & 63;
  #pragma unroll
  for (int j = 0; j < 32; j++) {
    float a = wsum(sum[j]);
    float b = wsum(ssq[j]);
    if (lane == 0) { red[wid * 64 + j] = a; red[wid * 64 + 32 + j] = b; }
  }
  __syncthreads();
  if (threadIdx.x < 64) {
    float t = red[threadIdx.x] + red[64 + threadIdx.x] + red[128 + threadIdx.x] + red[192 + threadIdx.x];
    if (threadIdx.x < 32) unsafeAtomicAdd(&gsum[threadIdx.x], t);
    else                  unsafeAtomicAdd(&gssq[threadIdx.x - 32], t);
  }
}

__device__ __forceinline__ void loadrow(const float* __restrict__ xp, int s, float in[13]) {
  const float4* xr = reinterpret_cast<const float4*>(xp + (size_t)s * 12);
  float4 r0 = xr[0], r1 = xr[1], r2 = xr[2];
  in[0]=r0.x; in[1]=r0.y; in[2]=r0.z; in[3]=r0.w; in[4]=r1.x; in[5]=r1.y; in[6]=r1.z; in[7]=r1.w;
  in[8]=r2.x; in[9]=r2.y; in[10]=r2.z;
}

// ---------- setup kernels ----------

// w2tf[j][k] = d_j * w1b[k][j] (d_j = sign(g1b_j)); b1bf[j] = d_j*b1b[j];
// w2aT[j][0..42]+bias at 43; wpaT[j][0..10]+bias at 11
__global__ __launch_bounds__(256) void k_wprep(const float* __restrict__ w1b,
    const float* __restrict__ b1b, const float* __restrict__ g1b,
    const float* __restrict__ w2a, const float* __restrict__ b2a,
    const float* __restrict__ wpa, const float* __restrict__ bpa,
    float* __restrict__ w2tf, float* __restrict__ b1bf,
    float* __restrict__ w2aT, float* __restrict__ wpaT) {
  int t = threadIdx.x;
  for (int i = t; i < 1024; i += 256) {
    int j = i >> 5, k = i & 31;
    float d = (g1b[j] >= 0.f) ? 1.f : -1.f;
    w2tf[j * 32 + k] = d * w1b[k * 32 + j];
  }
  for (int i = t; i < 32 * 43; i += 256) { int j = i & 31, k = i >> 5; w2aT[j * 44 + k] = w2a[k * 32 + j]; }
  for (int i = t; i < 32 * 11; i += 256) { int j = i & 31, k = i >> 5; wpaT[j * 12 + k] = wpa[k * 32 + j]; }
  if (t < 32) {
    float d = (g1b[t] >= 0.f) ? 1.f : -1.f;
    b1bf[t] = d * b1b[t];
    w2aT[t * 44 + 43] = b2a[t];
    wpaT[t * 12 + 11] = bpa[t];
  }
}

// one edge pass: cnt atomic (returned value = rank within dst, stored contiguously),
// packed src-side stats nsd[n]={deg(int),seaX,seaY,pad} (3 atomics -> same 64B line), ea moments
__global__ __launch_bounds__(256) void k_prep(const int* __restrict__ dst, const int* __restrict__ src,
    const float* __restrict__ ea, int* __restrict__ cnt, int* __restrict__ rank,
    float* __restrict__ nsd, float* __restrict__ cmom) {
  float p0 = 0, p1 = 0, p2 = 0, p3 = 0, p4 = 0;
  const int S = gridDim.x * 256;
  for (int g = blockIdx.x * 256 + threadIdx.x; g < EE / 4; g += S) {
    int4 d4 = reinterpret_cast<const int4*>(dst)[g];
    int4 s4 = reinterpret_cast<const int4*>(src)[g];
    float4 e0 = reinterpret_cast<const float4*>(ea)[2 * g];
    float4 e1 = reinterpret_cast<const float4*>(ea)[2 * g + 1];
    int r0 = atomicAdd(&cnt[d4.x], 1);
    int r1 = atomicAdd(&cnt[d4.y], 1);
    int r2 = atomicAdd(&cnt[d4.z], 1);
    int r3 = atomicAdd(&cnt[d4.w], 1);
    reinterpret_cast<int4*>(rank)[g] = make_int4(r0, r1, r2, r3);
    atomicAdd(reinterpret_cast<int*>(&nsd[4 * s4.x]), 1);
    unsafeAtomicAdd(&nsd[4 * s4.x + 1], e0.x); unsafeAtomicAdd(&nsd[4 * s4.x + 2], e0.y);
    atomicAdd(reinterpret_cast<int*>(&nsd[4 * s4.y]), 1);
    unsafeAtomicAdd(&nsd[4 * s4.y + 1], e0.z); unsafeAtomicAdd(&nsd[4 * s4.y + 2], e0.w);
    atomicAdd(reinterpret_cast<int*>(&nsd[4 * s4.z]), 1);
    unsafeAtomicAdd(&nsd[4 * s4.z + 1], e1.x); unsafeAtomicAdd(&nsd[4 * s4.z + 2], e1.y);
    atomicAdd(reinterpret_cast<int*>(&nsd[4 * s4.w]), 1);
    unsafeAtomicAdd(&nsd[4 * s4.w + 1], e1.z); unsafeAtomicAdd(&nsd[4 * s4.w + 2], e1.w);
    p0 += e0.x * e0.x + e0.z * e0.z + e1.x * e1.x + e1.z * e1.z;
    p1 += e0.x * e0.y + e0.z * e0.w + e1.x * e1.y + e1.z * e1.w;
    p2 += e0.y * e0.y + e0.w * e0.w + e1.y * e1.y + e1.w * e1.w;
    p3 += e0.x + e0.z + e1.x + e1.z;
    p4 += e0.y + e0.w + e1.y + e1.w;
  }
  p0 = wsum(p0); p1 = wsum(p1); p2 = wsum(p2); p3 = wsum(p3); p4 = wsum(p4);
  if ((threadIdx.x & 63) == 0) {
    unsafeAtomicAdd(&cmom[0], p0); unsafeAtomicAdd(&cmom[1], p1); unsafeAtomicAdd(&cmom[2], p2);
    unsafeAtomicAdd(&cmom[3], p3); unsafeAtomicAdd(&cmom[4], p4);
  }
}

__global__ __launch_bounds__(1024) void k_scan(const int* __restrict__ cnt,
                                               int* __restrict__ starts) {
  __shared__ int part[1024];
  const int T = 1024, CH = (NN + T - 1) / T;
  int t = threadIdx.x;
  int lo = t * CH, hi = min(lo + CH, NN);
  int s = 0;
  for (int i = lo; i < hi; i++) s += cnt[i];
  part[t] = s; __syncthreads();
  for (int off = 1; off < T; off <<= 1) {
    int v = (t >= off) ? part[t - off] : 0;
    __syncthreads();
    part[t] += v;
    __syncthreads();
  }
  int run = part[t] - s;  // exclusive prefix
  for (int i = lo; i < hi; i++) { starts[i] = run; run += cnt[i]; }
  if (t == T - 1) starts[NN] = EE;
}

// scatter packed 16B edge records (src, ea.x, ea.y, 0) into CSR order; NO atomics:
// pos = starts[dst] + rank (rank captured from the cnt atomic in k_prep)
__global__ __launch_bounds__(256) void k_scatter(const int* __restrict__ dst, const int* __restrict__ src,
    const float* __restrict__ ea, const int* __restrict__ starts, const int* __restrict__ rank,
    int4* __restrict__ edg) {
  const int S = gridDim.x * 256;
  for (int g = blockIdx.x * 256 + threadIdx.x; g < EE / 4; g += S) {
    int4 d4 = reinterpret_cast<const int4*>(dst)[g];
    int4 s4 = reinterpret_cast<const int4*>(src)[g];
    int4 r4 = reinterpret_cast<const int4*>(rank)[g];
    float4 e0 = reinterpret_cast<const float4*>(ea)[2 * g];
    float4 e1 = reinterpret_cast<const float4*>(ea)[2 * g + 1];
    edg[starts[d4.x] + r4.x] = make_int4(s4.x, __float_as_int(e0.x), __float_as_int(e0.y), 0);
    edg[starts[d4.y] + r4.y] = make_int4(s4.y, __float_as_int(e0.z), __float_as_int(e0.w), 0);
    edg[starts[d4.z] + r4.z] = make_int4(s4.z, __float_as_int(e1.x), __float_as_int(e1.y), 0);
    edg[starts[d4.w] + r4.w] = make_int4(s4.w, __float_as_int(e1.z), __float_as_int(e1.w), 0);
  }
}

// padded node rows: xp[n][0..9]=x cols 0..9, [10]=x col10 (current), [11]=0
__global__ __launch_bounds__(256) void k_xp(const float* __restrict__ x, float* __restrict__ xp) {
  int n = blockIdx.x * 256 + threadIdx.x;
  if (n >= NN) return;
  float v[11];
  #pragma unroll
  for (int k = 0; k < 11; k++) v[k] = x[(size_t)n * 11 + k];
  float4* o = reinterpret_cast<float4*>(xp + (size_t)n * 12);
  o[0] = make_float4(v[0], v[1], v[2], v[3]);
  o[1] = make_float4(v[4], v[5], v[6], v[7]);
  o[2] = make_float4(v[8], v[9], v[10], 0.f);
}

// ---------- per-conv: input moments (node pass) ----------
// mom layout: [0..10]=S_x (deg-weighted), [11..76]=sxx upper-tri(11), [77..98]=sxe
__global__ __launch_bounds__(256) void k_mom(const float* __restrict__ xp, const float* __restrict__ nsd,
                                             float* __restrict__ mom) {
  const int n = blockIdx.x * 256 + threadIdx.x;
  const int lane = threadIdx.x & 63;
  float v[11]; float w = 0.f; float sx = 0.f, sy = 0.f;
  #pragma unroll
  for (int k = 0; k < 11; k++) v[k] = 0.f;
  if (n < NN) {
    float4 nv = reinterpret_cast<const float4*>(nsd)[n];
    w = (float)__float_as_int(nv.x);
    sx = nv.y; sy = nv.z;
    loadrow(xp, n, v);
  }
  int ch = 0;
  #pragma unroll
  for (int a = 0; a < 11; a++) {
    float r = wsum(w * v[a]);
    if (lane == 0) unsafeAtomicAdd(&mom[ch], r);
    ch++;
  }
  #pragma unroll
  for (int a = 0; a < 11; a++) {
    #pragma unroll
    for (int b = a; b < 11; b++) {
      float r = wsum(w * v[a] * v[b]);
      if (lane == 0) unsafeAtomicAdd(&mom[ch], r);
      ch++;
    }
  }
  #pragma unroll
  for (int a = 0; a < 11; a++) {
    float rx = wsum(v[a] * sx);
    if (lane == 0) unsafeAtomicAdd(&mom[ch], rx);
    ch++;
    float ry = wsum(v[a] * sy);
    if (lane == 0) unsafeAtomicAdd(&mom[ch], ry);
    ch++;
  }
}

__device__ __forceinline__ float msym(const float* mom, const float* cmom, int k, int l) {
  int a = min(k, l), b = max(k, l);
  if (b < 11) return mom[11 + a * 11 - a * (a - 1) / 2 + (b - a)];
  if (a < 11) return mom[77 + a * 2 + (b - 11)];
  return cmom[(a - 11) + (b - 11)];
}

// layer-1 BN params from moments; emit FOLDED transposed weights w1f[j][0..12]+bias[13]
// plus compact edge-attr weight arrays wexy[0..31]=A*w[11], wexy[32..63]=A*w[12]; zero mom.
__global__ void k_fin1(float* __restrict__ mom, const float* __restrict__ cmom,
    const float* __restrict__ w1a, const float* __restrict__ b1a,
    const float* __restrict__ g1a, const float* __restrict__ be1a,
    float* __restrict__ w1f, float* __restrict__ wexy) {
  int j = threadIdx.x;  // 32 threads
  float w[13], S[13];
  #pragma unroll
  for (int k = 0; k < 13; k++) w[k] = w1a[k * 32 + j];
  #pragma unroll
  for (int k = 0; k < 11; k++) S[k] = mom[k];
  S[11] = cmom[3]; S[12] = cmom[4];
  float lin = 0.f;
  #pragma unroll
  for (int k = 0; k < 13; k++) lin = fmaf(w[k], S[k], lin);
  float quad = 0.f;
  #pragma unroll
  for (int k = 0; k < 13; k++)
    #pragma unroll
    for (int l = 0; l < 13; l++) quad = fmaf(w[k] * w[l], msym(mom, cmom, k, l), quad);
  const float invE = 1.f / EF;
  float b = b1a[j];
  float mean = fmaf(lin, invE, b);
  float ey2 = (quad + 2.f * b * lin) * invE + b * b;
  float var = fmaxf(ey2 - mean * mean, 0.f);
  float A = g1a[j] * rsqrtf(var + 1e-5f);
  float C = be1a[j] - mean * A;
  #pragma unroll
  for (int k = 0; k < 13; k++) w1f[j * 16 + k] = A * w[k];
  w1f[j * 16 + 13] = fmaf(A, b, C);
  w1f[j * 16 + 14] = 0.f; w1f[j * 16 + 15] = 0.f;
  wexy[j] = A * w[11];
  wexy[32 + j] = A * w[12];
  __syncthreads();
  for (int i = j; i < 128; i += 32) mom[i] = 0.f;
}

// P[n][32] = folded layer-1 pre-activation from node features only (edge attrs added per edge)
__global__ __launch_bounds__(256) void k_P(const float* __restrict__ xp, const float* __restrict__ w1f,
                                           float* __restrict__ P) {
  const int n = blockIdx.x * 256 + threadIdx.x;
  if (n >= NN) return;
  float xv[11];
  loadrow(xp, n, xv);
  float4* op = reinterpret_cast<float4*>(P + (size_t)n * 32);
  #pragma unroll
  for (int jj = 0; jj < 8; jj++) {
    float o[4];
    #pragma unroll
    for (int u = 0; u < 4; u++) {
      int j = 4 * jj + u;
      const float* wr = w1f + j * 16;
      float acc = wr[13];
      #pragma unroll
      for (int k = 0; k < 11; k++) acc = fmaf(xv[k], wr[k], acc);
      o[u] = acc;
    }
    op[jj] = make_float4(o[0], o[1], o[2], o[3]);
  }
}

// ---------- fused edge pass: lane = channel, weights register-resident ----------
// Each 32-lane half-wave owns ONE node; lane j owns channel j and holds W column j
// (= w2tf row j, 32 floats) in VGPRs, loaded once. Per edge: lane j computes m_j,
// the 32 m's are exchanged via a 128B LDS slot (1 ds_write + 8 broadcast b128 reads),
// then z_j = 32 register FMAs. Per-channel stats are lane-local scalars.
__global__ __launch_bounds__(256, 6) void k_fusedagg(
    const int* __restrict__ starts, const int4* __restrict__ edg,
    const float* __restrict__ P, const float* __restrict__ wexy,
    const float* __restrict__ w2tf, const float* __restrict__ b1bf,
    float* __restrict__ tzb, float* __restrict__ gms, float* __restrict__ gzq) {
  __shared__ float smx[4][2][32];
  __shared__ float redm[4][32], redq[4][32];
  const int tid = threadIdx.x;
  const int wid = tid >> 6, lane = tid & 63;
  const int half = lane >> 5, j = lane & 31;
  const int n = blockIdx.x * 8 + wid * 2 + half;   // NN = 12500*8 exactly
  // per-lane channel constants (loaded once; coalesced)
  const float wex = wexy[j], wey = wexy[32 + j], bz = b1bf[j];
  const float4* wc = reinterpret_cast<const float4*>(w2tf + (size_t)j * 32);
  const float4 wv0 = wc[0], wv1 = wc[1], wv2 = wc[2], wv3 = wc[3];
  const float4 wv4 = wc[4], wv5 = wc[5], wv6 = wc[6], wv7 = wc[7];
  float tz = -3.0e38f, zq = 0.f, ms = 0.f;
  int lo = 0, hi = 0;
  if (n < NN) { lo = starts[n]; hi = starts[n + 1]; }
  float* msl = &smx[wid][half][0];
  int sl = lo;
  int4 eA = make_int4(0, 0, 0, 0), eB = make_int4(0, 0, 0, 0);
  float pA = 0.f;
  if (sl < hi) {
    eA = edg[sl];
    pA = P[(size_t)eA.x * 32 + j];
  }
  if (sl + 1 < hi) eB = edg[sl + 1];
  while (sl < hi) {
    // prefetch (independent of current compute): edge i+2 record, edge i+1 P value
    int4 eC = eB;
    if (sl + 2 < hi) eC = edg[sl + 2];
    float pN = pA;
    if (sl + 1 < hi) pN = P[(size_t)eB.x * 32 + j];
    // current edge
    const float ex = __int_as_float(eA.y), ey = __int_as_float(eA.z);
    const float m = fmaxf(0.f, fmaf(ex, wex, fmaf(ey, wey, pA)));
    ms += m;
    msl[j] = m;
    __builtin_amdgcn_wave_barrier();
    const float4 m0 = *reinterpret_cast<const float4*>(msl + 0);
    const float4 m1 = *reinterpret_cast<const float4*>(msl + 4);
    const float4 m2 = *reinterpret_cast<const float4*>(msl + 8);
    const float4 m3 = *reinterpret_cast<const float4*>(msl + 12);
    const float4 m4 = *reinterpret_cast<const float4*>(msl + 16);
    const float4 m5 = *reinterpret_cast<const float4*>(msl + 20);
    const float4 m6 = *reinterpret_cast<const float4*>(msl + 24);
    const float4 m7 = *reinterpret_cast<const float4*>(msl + 28);
    __builtin_amdgcn_wave_barrier();
    float z0 = bz, z1 = 0.f, z2 = 0.f, z3 = 0.f;
    z0 = fmaf(m0.x, wv0.x, z0); z1 = fmaf(m0.y, wv0.y, z1);
    z2 = fmaf(m0.z, wv0.z, z2); z3 = fmaf(m0.w, wv0.w, z3);
    z0 = fmaf(m1.x, wv1.x, z0); z1 = fmaf(m1.y, wv1.y, z1);
    z2 = fmaf(m1.z, wv1.z, z2); z3 = fmaf(m1.w, wv1.w, z3);
    z0 = fmaf(m2.x, wv2.x, z0); z1 = fmaf(m2.y, wv2.y, z1);
    z2 = fmaf(m2.z, wv2.z, z2); z3 = fmaf(m2.w, wv2.w, z3);
    z0 = fmaf(m3.x, wv3.x, z0); z1 = fmaf(m3.y, wv3.y, z1);
    z2 = fmaf(m3.z, wv3.z, z2); z3 = fmaf(m3.w, wv3.w, z3);
    z0 = fmaf(m4.x, wv4.x, z0); z1 = fmaf(m4.y, wv4.y, z1);
    z2 = fmaf(m4.z, wv4.z, z2); z3 = fmaf(m4.w, wv4.w, z3);
    z0 = fmaf(m5.x, wv5.x, z0); z1 = fmaf(m5.y, wv5.y, z1);
    z2 = fmaf(m5.z, wv5.z, z2); z3 = fmaf(m5.w, wv5.w, z3);
    z0 = fmaf(m6.x, wv6.x, z0); z1 = fmaf(m6.y, wv6.y, z1);
    z2 = fmaf(m6.z, wv6.z, z2); z3 = fmaf(m6.w, wv6.w, z3);
    z0 = fmaf(m7.x, wv7.x, z0); z1 = fmaf(m7.y, wv7.y, z1);
    z2 = fmaf(m7.z, wv7.z, z2); z3 = fmaf(m7.w, wv7.w, z3);
    const float z = (z0 + z1) + (z2 + z3);
    tz = fmaxf(tz, z);
    zq = fmaf(z, z, zq);
    // rotate pipeline
    eA = eB; eB = eC; pA = pN;
    ++sl;
  }
  // write per-node channel max (lane j -> tzb[n*32+j], coalesced per half)
  if (n < NN) tzb[(size_t)n * 32 + j] = tz;
  // stats: combine halves (same channel j), then block-reduce, then binned atomics
  float msT = ms + __shfl_xor(ms, 32, 64);
  float zqT = zq + __shfl_xor(zq, 32, 64);
  if (lane < 32) { redm[wid][j] = msT; redq[wid][j] = zqT; }
  __syncthreads();
  if (tid < 32) {
    float a = redm[0][tid] + redm[1][tid] + redm[2][tid] + redm[3][tid];
    float b = redq[0][tid] + redq[1][tid] + redq[2][tid] + redq[3][tid];
    const int bin = blockIdx.x & (NBIN - 1);
    unsafeAtomicAdd(&gms[bin * 32 + tid], a);
    unsafeAtomicAdd(&gzq[bin * 32 + tid], b);
  }
}

// layer-2 BN from binned stats: zs_j = w1b[:,j]·ms + E*b1b_j; A2d = A2*sign(g1b); zero bins
__global__ void k_fin2(float* __restrict__ gms, float* __restrict__ gzq,
    const float* __restrict__ w1b, const float* __restrict__ b1b,
    const float* __restrict__ g1b, const float* __restrict__ be1b,
    float* __restrict__ A2d, float* __restrict__ C2) {
  __shared__ float sm[32];
  int j = threadIdx.x;  // 32 threads
  float msj = 0.f, zqj = 0.f;
  for (int b = 0; b < NBIN; b++) { msj += gms[b * 32 + j]; zqj += gzq[b * 32 + j]; }
  sm[j] = msj;
  __syncthreads();
  float zs = EF * b1b[j];
  #pragma unroll
  for (int k = 0; k < 32; k++) zs = fmaf(w1b[k * 32 + j], sm[k], zs);
  const float invE = 1.f / EF;
  float mu = zs * invE;
  float var = fmaxf(zqj * invE - mu * mu, 0.f);
  float A = g1b[j] * rsqrtf(var + 1e-5f);
  float C = be1b[j] - mu * A;
  float d = (g1b[j] >= 0.f) ? 1.f : -1.f;
  A2d[j] = A * d; C2[j] = C;
  for (int b = 0; b < NBIN; b++) { gms[b * 32 + j] = 0.f; gzq[b * 32 + j] = 0.f; }
}

// BN finalize: a = g*rsqrt(var+eps), c = be - mu*a; zero sums for reuse
__global__ void k_finalize(float* __restrict__ sum, float* __restrict__ ssq,
                           const float* __restrict__ g, const float* __restrict__ be,
                           float inv_n, int ncols, float* __restrict__ a, float* __restrict__ c) {
  int j = threadIdx.x;
  if (j < ncols) {
    float mu = sum[j] * inv_n;
    float var = fmaxf(ssq[j] * inv_n - mu * mu, 0.f);
    float s = rsqrtf(var + 1e-5f) * g[j];
    a[j] = s; c[j] = be[j] - mu * s;
    sum[j] = 0.f; ssq[j] = 0.f;
  }
}

// ---------- agg finalize + h_pre = [x, agg] @ w2a + b2a (+stats) ----------

__global__ __launch_bounds__(256) void k_hpre2(const float* __restrict__ xp,
    const float* __restrict__ tzb, const int* __restrict__ starts,
    const float* __restrict__ A2d, const float* __restrict__ C2, const float* __restrict__ w2aT,
    float* __restrict__ hpre, float* __restrict__ gsum, float* __restrict__ gssq) {
  __shared__ float red[256];
  const int n = blockIdx.x * 256 + threadIdx.x;
  float h[32], hh[32];
  #pragma unroll
  for (int j = 0; j < 32; j++) h[j] = 0.f;
  if (n < NN) {
    float xv[11];
    loadrow(xp, n, xv);
    const int dg = starts[n + 1] - starts[n];
    float av[32];
    if (dg > 0) {
      const float4* tp = reinterpret_cast<const float4*>(tzb + (size_t)n * 32);
      #pragma unroll
      for (int j = 0; j < 8; j++) {
        float4 v = tp[j];
        av[4 * j]     = fmaxf(0.f, fmaf(A2d[4 * j],     v.x, C2[4 * j]));
        av[4 * j + 1] = fmaxf(0.f, fmaf(A2d[4 * j + 1], v.y, C2[4 * j + 1]));
        av[4 * j + 2] = fmaxf(0.f, fmaf(A2d[4 * j + 2], v.z, C2[4 * j + 2]));
        av[4 * j + 3] = fmaxf(0.f, fmaf(A2d[4 * j + 3], v.w, C2[4 * j + 3]));
      }
    } else {
      #pragma unroll
      for (int j = 0; j < 32; j++) av[j] = 0.f;
    }
    #pragma unroll
    for (int j = 0; j < 32; j++) {
      const float* wr = w2aT + j * 44;
      float acc = wr[43];
      #pragma unroll
      for (int k = 0; k < 11; k++) acc = fmaf(xv[k], wr[k], acc);
      #pragma unroll
      for (int k = 0; k < 32; k++) acc = fmaf(av[k], wr[11 + k], acc);
      h[j] = acc;
    }
    float4* hp = reinterpret_cast<float4*>(hpre + (size_t)n * 32);
    #pragma unroll
    for (int j = 0; j < 8; j++)
      hp[j] = make_float4(h[4 * j], h[4 * j + 1], h[4 * j + 2], h[4 * j + 3]);
  }
  #pragma unroll
  for (int j = 0; j < 32; j++) hh[j] = h[j] * h[j];
  reduce64(h, hh, red, gsum, gssq);
}

// comb = relu(relu(bn(h_pre)) @ w2b + b2b) -> xp col 10
__global__ __launch_bounds__(256) void k_comb(const float* __restrict__ hpre,
    const float* __restrict__ a3, const float* __restrict__ c3,
    const float* __restrict__ w2b, const float* __restrict__ b2b, float* __restrict__ xp) {
  const int n = blockIdx.x * 256 + threadIdx.x;
  if (n >= NN) return;
  const float4* hp = reinterpret_cast<const float4*>(hpre + (size_t)n * 32);
  float acc = b2b[0];
  #pragma unroll
  for (int j = 0; j < 8; j++) {
    float4 v = hp[j];
    acc += fmaxf(0.f, fmaf(v.x, a3[4 * j],     c3[4 * j]))     * w2b[4 * j];
    acc += fmaxf(0.f, fmaf(v.y, a3[4 * j + 1], c3[4 * j + 1])) * w2b[4 * j + 1];
    acc += fmaxf(0.f, fmaf(v.z, a3[4 * j + 2], c3[4 * j + 2])) * w2b[4 * j + 2];
    acc += fmaxf(0.f, fmaf(v.w, a3[4 * j + 3], c3[4 * j + 3])) * w2b[4 * j + 3];
  }
  xp[(size_t)n * 12 + 10] = fmaxf(acc, 0.f);
}

// ---------- power MLP ----------

// yp = x @ wpa + bpa : store to ybuf + stats
__global__ __launch_bounds__(256) void k_p5(const float* __restrict__ xp, const float* __restrict__ wpaT,
                                            float* __restrict__ ybuf,
                                            float* __restrict__ gsum, float* __restrict__ gssq) {
  __shared__ float red[256];
  const int n = blockIdx.x * 256 + threadIdx.x;
  float y[32], yy[32];
  #pragma unroll
  for (int j = 0; j < 32; j++) y[j] = 0.f;
  if (n < NN) {
    float xv[11];
    loadrow(xp, n, xv);
    #pragma unroll
    for (int j = 0; j < 32; j++) {
      const float* wr = wpaT + j * 12;
      float acc = wr[11];
      #pragma unroll
      for (int k = 0; k < 11; k++) acc = fmaf(xv[k], wr[k], acc);
      y[j] = acc;
    }
    float4* yp = reinterpret_cast<float4*>(ybuf + (size_t)n * 32);
    #pragma unroll
    for (int j = 0; j < 8; j++)
      yp[j] = make_float4(y[4 * j], y[4 * j + 1], y[4 * j + 2], y[4 * j + 3]);
  }
  #pragma unroll
  for (int j = 0; j < 32; j++) yy[j] = y[j] * y[j];
  reduce64(y, yy, red, gsum, gssq);
}

// yq = relu(bn(yp)) @ wpb + bpb : store + scalar stats (reads stored yp)
__global__ __launch_bounds__(256) void k_p6(const float* __restrict__ ybuf,
    const float* __restrict__ a4, const float* __restrict__ c4,
    const float* __restrict__ wpb, const float* __restrict__ bpb,
    float* __restrict__ yq, float* __restrict__ gsum, float* __restrict__ gssq) {
  __shared__ float red[8];
  const int n = blockIdx.x * 256 + threadIdx.x;
  float sum = 0.f, ssq = 0.f;
  if (n < NN) {
    const float4* yp = reinterpret_cast<const float4*>(ybuf + (size_t)n * 32);
    float q = bpb[0];
    #pragma unroll
    for (int j = 0; j < 8; j++) {
      float4 v = yp[j];
      q = fmaf(fmaxf(0.f, fmaf(v.x, a4[4 * j],     c4[4 * j])),     wpb[4 * j],     q);
      q = fmaf(fmaxf(0.f, fmaf(v.y, a4[4 * j + 1], c4[4 * j + 1])), wpb[4 * j + 1], q);
      q = fmaf(fmaxf(0.f, fmaf(v.z, a4[4 * j + 2], c4[4 * j + 2])), wpb[4 * j + 2], q);
      q = fmaf(fmaxf(0.f, fmaf(v.w, a4[4 * j + 3], c4[4 * j + 3])), wpb[4 * j + 3], q);
    }
    yq[n] = q;
    sum = q; ssq = q * q;
  }
  float s = wsum(sum), qq = wsum(ssq);
  const int wid = threadIdx.x >> 6, lane = threadIdx.x & 63;
  if (lane == 0) { red[wid] = s; red[4 + wid] = qq; }
  __syncthreads();
  if (threadIdx.x == 0) {
    unsafeAtomicAdd(&gsum[0], red[0] + red[1] + red[2] + red[3]);
    unsafeAtomicAdd(&gssq[0], red[4] + red[5] + red[6] + red[7]);
  }
}

__global__ __launch_bounds__(256) void k_p7(const float* __restrict__ yq,
    const float* __restrict__ a5, const float* __restrict__ c5, float* __restrict__ out) {
  int n = blockIdx.x * 256 + threadIdx.x;
  if (n < NN) out[n] = fmaxf(0.f, fmaf(yq[n], a5[0], c5[0]));
}

// ---------- host launch ----------

extern "C" void kernel_launch(void* const* d_in, const int* in_sizes, int n_in,
                              void* d_out, int out_size, void* d_ws, size_t ws_size,
                              hipStream_t stream) {
  const float* x    = (const float*)d_in[0];
  const float* ea   = (const float*)d_in[1];
  const int*   ei   = (const int*)d_in[2];
  const int*   srcp = ei;
  const int*   dstp = ei + EE;
  const float* w1a = (const float*)d_in[3],  *b1a = (const float*)d_in[4];
  const float* g1a = (const float*)d_in[5],  *be1a = (const float*)d_in[6];
  const float* w1b = (const float*)d_in[7],  *b1b = (const float*)d_in[8];
  const float* g1b = (const float*)d_in[9],  *be1b = (const float*)d_in[10];
  const float* w2a = (const float*)d_in[11], *b2a = (const float*)d_in[12];
  const float* g2a = (const float*)d_in[13], *be2a = (const float*)d_in[14];
  const float* w2b = (const float*)d_in[15], *b2b = (const float*)d_in[16];
  const float* wpa = (const float*)d_in[17], *bpa = (const float*)d_in[18];
  const float* gpa = (const float*)d_in[19], *bepa = (const float*)d_in[20];
  const float* wpb = (const float*)d_in[21], *bpb = (const float*)d_in[22];
  const float* gpb = (const float*)d_in[23], *bepb = (const float*)d_in[24];

  size_t off = 0;
  char* base = (char*)d_ws;
  auto alloc = [&](size_t bytes) -> void* {
    void* p = base + off;
    off += (bytes + 255) & ~(size_t)255;
    return p;
  };
  float* stats = (float*)alloc(2048);
  float* coef  = (float*)alloc(2048);
  float* mom   = (float*)alloc(512);
  float* cmom  = (float*)alloc(256);
  float* gmsB  = (float*)alloc(NBIN * 32 * 4);
  float* gzqB  = (float*)alloc(NBIN * 32 * 4);
  float* w1f   = (float*)alloc(16 * 32 * 4);
  float* wexy  = (float*)alloc(64 * 4);
  float* w2tf  = (float*)alloc(32 * 32 * 4);
  float* b1bf  = (float*)alloc(256);
  float* w2aT  = (float*)alloc(32 * 44 * 4);
  float* wpaT  = (float*)alloc(32 * 12 * 4);
  int*   cnt    = (int*)alloc(NN * 4);
  float* nsd    = (float*)alloc((size_t)NN * 4 * 4);
  int*   starts = (int*)alloc((NN + 1) * 4);
  int*   rank   = (int*)alloc((size_t)EE * 4);
  int4*  edg    = (int4*)alloc((size_t)EE * 16);
  float* xp     = (float*)alloc((size_t)NN * 12 * 4);
  float* P      = (float*)alloc((size_t)NN * 32 * 4);
  float* tzb    = (float*)alloc((size_t)NN * 32 * 4);
  float* hpre   = (float*)alloc((size_t)NN * 32 * 4);
  float* yq     = (float*)alloc(NN * 4);

  float *SUM3 = stats + 64,  *SSQ3 = stats + 96;
  float *SUM4 = stats + 128, *SSQ4 = stats + 160;
  float *SUM5 = stats + 192, *SSQ5 = stats + 224;
  float *A2d = coef,       *C2 = coef + 32;
  float *A3  = coef + 64,  *C3 = coef + 96;
  float *A4  = coef + 128, *C4 = coef + 160;
  float *A5  = coef + 192, *C5 = coef + 224;

  hipMemsetAsync(stats, 0, 2048, stream);
  hipMemsetAsync(mom, 0, 512 + 256, stream);               // mom + cmom (contiguous)
  hipMemsetAsync(gmsB, 0, NBIN * 32 * 4 * 2, stream);      // gmsB + gzqB (contiguous)
  hipMemsetAsync(cnt, 0, NN * 4, stream);
  hipMemsetAsync(nsd, 0, (size_t)NN * 4 * 4, stream);

  const int GN = (NN + 255) / 256;          // 391
  const int GW = NN / 8;                    // 12500 blocks: 8 nodes x (4 waves x 2 halves)
  const int GE4 = (EE / 4 + 255) / 256;     // 3125

  k_wprep  <<<1, 256, 0, stream>>>(w1b, b1b, g1b, w2a, b2a, wpa, bpa, w2tf, b1bf, w2aT, wpaT);
  k_prep   <<<GE4, 256, 0, stream>>>(dstp, srcp, ea, cnt, rank, nsd, cmom);
  k_scan   <<<1, 1024, 0, stream>>>(cnt, starts);
  k_scatter<<<GE4, 256, 0, stream>>>(dstp, srcp, ea, starts, rank, edg);
  k_xp     <<<GN, 256, 0, stream>>>(x, xp);

  const float invN = 1.f / (float)NN;
  for (int c = 0; c < 3; c++) {
    k_mom     <<<GN, 256, 0, stream>>>(xp, nsd, mom);
    k_fin1    <<<1, 32, 0, stream>>>(mom, cmom, w1a, b1a, g1a, be1a, w1f, wexy);
    k_P       <<<GN, 256, 0, stream>>>(xp, w1f, P);
    k_fusedagg<<<GW, 256, 0, stream>>>(starts, edg, P, wexy, w2tf, b1bf, tzb, gmsB, gzqB);
    k_fin2    <<<1, 32, 0, stream>>>(gmsB, gzqB, w1b, b1b, g1b, be1b, A2d, C2);
    k_hpre2   <<<GN, 256, 0, stream>>>(xp, tzb, starts, A2d, C2, w2aT, hpre, SUM3, SSQ3);
    k_finalize<<<1, 32, 0, stream>>>(SUM3, SSQ3, g2a, be2a, invN, 32, A3, C3);
    k_comb    <<<GN, 256, 0, stream>>>(hpre, A3, C3, w2b, b2b, xp);
  }

  k_p5      <<<GN, 256, 0, stream>>>(xp, wpaT, hpre, SUM4, SSQ4);
  k_finalize<<<1, 32, 0, stream>>>(SUM4, SSQ4, gpa, bepa, invN, 32, A4, C4);
  k_p6      <<<GN, 256, 0, stream>>>(hpre, A4, C4, wpb, bpb, yq, SUM5, SSQ5);
  k_finalize<<<1, 32, 0, stream>>>(SUM5, SSQ5, gpb, bepb, invN, 1, A5, C5);
  k_p7      <<<GN, 256, 0, stream>>>(yq, A5, C5, (float*)d_out);
}

// Round 9
// 3968.800 us; speedup vs baseline: 2.0067x; 1.0620x over previous
//
#include <hip/hip_runtime.h>
#include <hip/hip_bf16.h>
#include <cstddef>

#define NN 100000
#define EE 3200000
#define NBIN 64
static const float EF = 3200000.0f;

// ---------- helpers ----------

__device__ __forceinline__ float wsum(float v) {
  #pragma unroll
  for (int off = 32; off > 0; off >>= 1) v += __shfl_down(v, off, 64);
  return v;  // lane 0 holds wave total
}

// block-level reduce of 32 sums + 32 sumsq -> global atomics. red = shared float[256].
__device__ __forceinline__ void reduce64(float sum[32], float ssq[32], float* red,
                                         float* __restrict__ gsum, float* __restrict__ gssq) {
  const int wid = threadIdx.x >> 6, lane = threadIdx.x & 63;
  #pragma unroll
  for (int j = 0; j < 32; j++) {
    float a = wsum(sum[j]);
    float b = wsum(ssq[j]);
    if (lane == 0) { red[wid * 64 + j] = a; red[wid * 64 + 32 + j] = b; }
  }
  __syncthreads();
  if (threadIdx.x < 64) {
    float t = red[threadIdx.x] + red[64 + threadIdx.x] + red[128 + threadIdx.x] + red[192 + threadIdx.x];
    if (threadIdx.x < 32) unsafeAtomicAdd(&gsum[threadIdx.x], t);
    else                  unsafeAtomicAdd(&gssq[threadIdx.x - 32], t);
  }
}

__device__ __forceinline__ void loadrow(const float* __restrict__ xp, int s, float in[13]) {
  const float4* xr = reinterpret_cast<const float4*>(xp + (size_t)s * 12);
  float4 r0 = xr[0], r1 = xr[1], r2 = xr[2];
  in[0]=r0.x; in[1]=r0.y; in[2]=r0.z; in[3]=r0.w; in[4]=r1.x; in[5]=r1.y; in[6]=r1.z; in[7]=r1.w;
  in[8]=r2.x; in[9]=r2.y; in[10]=r2.z;
}

// pack one edge's src-side contribution: [deg:1 @bit54 | (ey+8)*2^14 @bit27 | (ex+8)*2^14 @bit0]
__device__ __forceinline__ unsigned long long packsea(float x, float y) {
  unsigned int xq = (unsigned int)(fmaf(x, 16384.f, 131072.f) + 0.5f);
  unsigned int yq = (unsigned int)(fmaf(y, 16384.f, 131072.f) + 0.5f);
  return (1ULL << 54) | ((unsigned long long)yq << 27) | (unsigned long long)xq;
}

// ---------- setup kernels ----------

// w2tf[j][k] = d_j * w1b[k][j] (d_j = sign(g1b_j)); b1bf[j] = d_j*b1b[j];
// w2aT[j][0..42]+bias at 43; wpaT[j][0..10]+bias at 11
__global__ __launch_bounds__(256) void k_wprep(const float* __restrict__ w1b,
    const float* __restrict__ b1b, const float* __restrict__ g1b,
    const float* __restrict__ w2a, const float* __restrict__ b2a,
    const float* __restrict__ wpa, const float* __restrict__ bpa,
    float* __restrict__ w2tf, float* __restrict__ b1bf,
    float* __restrict__ w2aT, float* __restrict__ wpaT) {
  int t = threadIdx.x;
  for (int i = t; i < 1024; i += 256) {
    int j = i >> 5, k = i & 31;
    float d = (g1b[j] >= 0.f) ? 1.f : -1.f;
    w2tf[j * 32 + k] = d * w1b[k * 32 + j];
  }
  for (int i = t; i < 32 * 43; i += 256) { int j = i & 31, k = i >> 5; w2aT[j * 44 + k] = w2a[k * 32 + j]; }
  for (int i = t; i < 32 * 11; i += 256) { int j = i & 31, k = i >> 5; wpaT[j * 12 + k] = wpa[k * 32 + j]; }
  if (t < 32) {
    float d = (g1b[t] >= 0.f) ? 1.f : -1.f;
    b1bf[t] = d * b1b[t];
    w2aT[t * 44 + 43] = b2a[t];
    wpaT[t * 12 + 11] = bpa[t];
  }
}

// one edge pass: cnt atomic (returned value = rank within dst, stored contiguously),
// ONE u64 fixed-point atomic for (deg, seaX, seaY) per edge, global ea moments in registers
__global__ __launch_bounds__(256) void k_prep(const int* __restrict__ dst, const int* __restrict__ src,
    const float* __restrict__ ea, int* __restrict__ cnt, int* __restrict__ rank,
    unsigned long long* __restrict__ nsd, float* __restrict__ cmom) {
  float p0 = 0, p1 = 0, p2 = 0, p3 = 0, p4 = 0;
  const int S = gridDim.x * 256;
  for (int g = blockIdx.x * 256 + threadIdx.x; g < EE / 4; g += S) {
    int4 d4 = reinterpret_cast<const int4*>(dst)[g];
    int4 s4 = reinterpret_cast<const int4*>(src)[g];
    float4 e0 = reinterpret_cast<const float4*>(ea)[2 * g];
    float4 e1 = reinterpret_cast<const float4*>(ea)[2 * g + 1];
    int r0 = atomicAdd(&cnt[d4.x], 1);
    int r1 = atomicAdd(&cnt[d4.y], 1);
    int r2 = atomicAdd(&cnt[d4.z], 1);
    int r3 = atomicAdd(&cnt[d4.w], 1);
    reinterpret_cast<int4*>(rank)[g] = make_int4(r0, r1, r2, r3);
    atomicAdd(&nsd[s4.x], packsea(e0.x, e0.y));
    atomicAdd(&nsd[s4.y], packsea(e0.z, e0.w));
    atomicAdd(&nsd[s4.z], packsea(e1.x, e1.y));
    atomicAdd(&nsd[s4.w], packsea(e1.z, e1.w));
    p0 += e0.x * e0.x + e0.z * e0.z + e1.x * e1.x + e1.z * e1.z;
    p1 += e0.x * e0.y + e0.z * e0.w + e1.x * e1.y + e1.z * e1.w;
    p2 += e0.y * e0.y + e0.w * e0.w + e1.y * e1.y + e1.w * e1.w;
    p3 += e0.x + e0.z + e1.x + e1.z;
    p4 += e0.y + e0.w + e1.y + e1.w;
  }
  p0 = wsum(p0); p1 = wsum(p1); p2 = wsum(p2); p3 = wsum(p3); p4 = wsum(p4);
  if ((threadIdx.x & 63) == 0) {
    unsafeAtomicAdd(&cmom[0], p0); unsafeAtomicAdd(&cmom[1], p1); unsafeAtomicAdd(&cmom[2], p2);
    unsafeAtomicAdd(&cmom[3], p3); unsafeAtomicAdd(&cmom[4], p4);
  }
}

__global__ __launch_bounds__(1024) void k_scan(const int* __restrict__ cnt,
                                               int* __restrict__ starts) {
  __shared__ int part[1024];
  const int T = 1024, CH = (NN + T - 1) / T;
  int t = threadIdx.x;
  int lo = t * CH, hi = min(lo + CH, NN);
  int s = 0;
  for (int i = lo; i < hi; i++) s += cnt[i];
  part[t] = s; __syncthreads();
  for (int off = 1; off < T; off <<= 1) {
    int v = (t >= off) ? part[t - off] : 0;
    __syncthreads();
    part[t] += v;
    __syncthreads();
  }
  int run = part[t] - s;  // exclusive prefix
  for (int i = lo; i < hi; i++) { starts[i] = run; run += cnt[i]; }
  if (t == T - 1) starts[NN] = EE;
}

// scatter packed 16B edge records (src, ea.x, ea.y, 0) into CSR order; NO atomics:
// pos = starts[dst] + rank (rank captured from the cnt atomic in k_prep)
__global__ __launch_bounds__(256) void k_scatter(const int* __restrict__ dst, const int* __restrict__ src,
    const float* __restrict__ ea, const int* __restrict__ starts, const int* __restrict__ rank,
    int4* __restrict__ edg) {
  const int S = gridDim.x * 256;
  for (int g = blockIdx.x * 256 + threadIdx.x; g < EE / 4; g += S) {
    int4 d4 = reinterpret_cast<const int4*>(dst)[g];
    int4 s4 = reinterpret_cast<const int4*>(src)[g];
    int4 r4 = reinterpret_cast<const int4*>(rank)[g];
    float4 e0 = reinterpret_cast<const float4*>(ea)[2 * g];
    float4 e1 = reinterpret_cast<const float4*>(ea)[2 * g + 1];
    edg[starts[d4.x] + r4.x] = make_int4(s4.x, __float_as_int(e0.x), __float_as_int(e0.y), 0);
    edg[starts[d4.y] + r4.y] = make_int4(s4.y, __float_as_int(e0.z), __float_as_int(e0.w), 0);
    edg[starts[d4.z] + r4.z] = make_int4(s4.z, __float_as_int(e1.x), __float_as_int(e1.y), 0);
    edg[starts[d4.w] + r4.w] = make_int4(s4.w, __float_as_int(e1.z), __float_as_int(e1.w), 0);
  }
}

// padded node rows: xp[n][0..9]=x cols 0..9, [10]=x col10 (current), [11]=0
__global__ __launch_bounds__(256) void k_xp(const float* __restrict__ x, float* __restrict__ xp) {
  int n = blockIdx.x * 256 + threadIdx.x;
  if (n >= NN) return;
  float v[11];
  #pragma unroll
  for (int k = 0; k < 11; k++) v[k] = x[(size_t)n * 11 + k];
  float4* o = reinterpret_cast<float4*>(xp + (size_t)n * 12);
  o[0] = make_float4(v[0], v[1], v[2], v[3]);
  o[1] = make_float4(v[4], v[5], v[6], v[7]);
  o[2] = make_float4(v[8], v[9], v[10], 0.f);
}

// ---------- per-conv: input moments (node pass) ----------
// mom layout: [0..10]=S_x (deg-weighted), [11..76]=sxx upper-tri(11), [77..98]=sxe
__global__ __launch_bounds__(256) void k_mom(const float* __restrict__ xp,
                                             const unsigned long long* __restrict__ nsd,
                                             float* __restrict__ mom) {
  const int n = blockIdx.x * 256 + threadIdx.x;
  const int lane = threadIdx.x & 63;
  float v[11]; float w = 0.f; float sx = 0.f, sy = 0.f;
  #pragma unroll
  for (int k = 0; k < 11; k++) v[k] = 0.f;
  if (n < NN) {
    unsigned long long pv = nsd[n];
    float dg = (float)(unsigned int)(pv >> 54);
    float sxf = (float)(unsigned int)(pv & 0x7FFFFFFull);
    float syf = (float)(unsigned int)((pv >> 27) & 0x7FFFFFFull);
    w = dg;
    sx = sxf * (1.f / 16384.f) - 8.f * dg;
    sy = syf * (1.f / 16384.f) - 8.f * dg;
    loadrow(xp, n, v);
  }
  int ch = 0;
  #pragma unroll
  for (int a = 0; a < 11; a++) {
    float r = wsum(w * v[a]);
    if (lane == 0) unsafeAtomicAdd(&mom[ch], r);
    ch++;
  }
  #pragma unroll
  for (int a = 0; a < 11; a++) {
    #pragma unroll
    for (int b = a; b < 11; b++) {
      float r = wsum(w * v[a] * v[b]);
      if (lane == 0) unsafeAtomicAdd(&mom[ch], r);
      ch++;
    }
  }
  #pragma unroll
  for (int a = 0; a < 11; a++) {
    float rx = wsum(v[a] * sx);
    if (lane == 0) unsafeAtomicAdd(&mom[ch], rx);
    ch++;
    float ry = wsum(v[a] * sy);
    if (lane == 0) unsafeAtomicAdd(&mom[ch], ry);
    ch++;
  }
}

__device__ __forceinline__ float msym(const float* mom, const float* cmom, int k, int l) {
  int a = min(k, l), b = max(k, l);
  if (b < 11) return mom[11 + a * 11 - a * (a - 1) / 2 + (b - a)];
  if (a < 11) return mom[77 + a * 2 + (b - 11)];
  return cmom[(a - 11) + (b - 11)];
}

// layer-1 BN params from moments; emit FOLDED transposed weights w1f[j][0..12]+bias[13]
// plus compact edge-attr weight arrays wexy[0..31]=A*w[11], wexy[32..63]=A*w[12]; zero mom.
__global__ void k_fin1(float* __restrict__ mom, const float* __restrict__ cmom,
    const float* __restrict__ w1a, const float* __restrict__ b1a,
    const float* __restrict__ g1a, const float* __restrict__ be1a,
    float* __restrict__ w1f, float* __restrict__ wexy) {
  int j = threadIdx.x;  // 32 threads
  float w[13], S[13];
  #pragma unroll
  for (int k = 0; k < 13; k++) w[k] = w1a[k * 32 + j];
  #pragma unroll
  for (int k = 0; k < 11; k++) S[k] = mom[k];
  S[11] = cmom[3]; S[12] = cmom[4];
  float lin = 0.f;
  #pragma unroll
  for (int k = 0; k < 13; k++) lin = fmaf(w[k], S[k], lin);
  float quad = 0.f;
  #pragma unroll
  for (int k = 0; k < 13; k++)
    #pragma unroll
    for (int l = 0; l < 13; l++) quad = fmaf(w[k] * w[l], msym(mom, cmom, k, l), quad);
  const float invE = 1.f / EF;
  float b = b1a[j];
  float mean = fmaf(lin, invE, b);
  float ey2 = (quad + 2.f * b * lin) * invE + b * b;
  float var = fmaxf(ey2 - mean * mean, 0.f);
  float A = g1a[j] * rsqrtf(var + 1e-5f);
  float C = be1a[j] - mean * A;
  #pragma unroll
  for (int k = 0; k < 13; k++) w1f[j * 16 + k] = A * w[k];
  w1f[j * 16 + 13] = fmaf(A, b, C);
  w1f[j * 16 + 14] = 0.f; w1f[j * 16 + 15] = 0.f;
  wexy[j] = A * w[11];
  wexy[32 + j] = A * w[12];
  __syncthreads();
  for (int i = j; i < 128; i += 32) mom[i] = 0.f;
}

// P[n][32] = folded layer-1 pre-activation from node features only (edge attrs added per edge)
__global__ __launch_bounds__(256) void k_P(const float* __restrict__ xp, const float* __restrict__ w1f,
                                           float* __restrict__ P) {
  const int n = blockIdx.x * 256 + threadIdx.x;
  if (n >= NN) return;
  float xv[11];
  loadrow(xp, n, xv);
  float4* op = reinterpret_cast<float4*>(P + (size_t)n * 32);
  #pragma unroll
  for (int jj = 0; jj < 8; jj++) {
    float o[4];
    #pragma unroll
    for (int u = 0; u < 4; u++) {
      int j = 4 * jj + u;
      const float* wr = w1f + j * 16;
      float acc = wr[13];
      #pragma unroll
      for (int k = 0; k < 11; k++) acc = fmaf(xv[k], wr[k], acc);
      o[u] = acc;
    }
    op[jj] = make_float4(o[0], o[1], o[2], o[3]);
  }
}

// ---------- fused edge pass: lane = channel, k-half split (fp32-exact) ----------
// Each 32-lane half-wave owns ONE node; lane l owns channel l. For the z-matvec, lane l
// holds rows [16h,16h+16) (h = l>>4) of W columns {l&15, (l&15)+16} (32 VGPRs), reads only
// its 64B half of the m-vector (4 b128/edge-pair, was 8), computes two 16-FMA partials,
// combines with shfl_xor(16). Final channel of lane l is exactly l -> stats unchanged.
__global__ __launch_bounds__(256, 6) void k_fusedagg(
    const int* __restrict__ starts, const int4* __restrict__ edg,
    const float* __restrict__ P, const float* __restrict__ wexy,
    const float* __restrict__ w2tf, const float* __restrict__ b1bf,
    float* __restrict__ tzb, float* __restrict__ gms, float* __restrict__ gzq) {
  __shared__ float smx[4][2][32];
  __shared__ float redm[4][32], redq[4][32];
  const int tid = threadIdx.x;
  const int wid = tid >> 6, lane = tid & 63;
  const int half = lane >> 5, l = lane & 31;
  const int c0 = l & 15, h = (l >> 4) & 1;
  const int n = blockIdx.x * 8 + wid * 2 + half;   // NN = 12500*8 exactly
  // per-lane channel constants (loaded once; coalesced)
  const float wex = wexy[l], wey = wexy[32 + l], bz = b1bf[l];
  const float4* wcA = reinterpret_cast<const float4*>(w2tf + (size_t)c0 * 32 + 16 * h);
  const float4* wcB = reinterpret_cast<const float4*>(w2tf + (size_t)(c0 + 16) * 32 + 16 * h);
  const float4 a0 = wcA[0], a1 = wcA[1], a2 = wcA[2], a3 = wcA[3];
  const float4 b0 = wcB[0], b1 = wcB[1], b2 = wcB[2], b3 = wcB[3];
  float tz = -3.0e38f, zq = 0.f, ms = 0.f;
  int lo = 0, hi = 0;
  if (n < NN) { lo = starts[n]; hi = starts[n + 1]; }
  float* msl = &smx[wid][half][0];
  const float* mrd = msl + 16 * h;
  int sl = lo;
  int4 eA = make_int4(0, 0, 0, 0), eB = make_int4(0, 0, 0, 0);
  float pA = 0.f;
  if (sl < hi) {
    eA = edg[sl];
    pA = P[(size_t)eA.x * 32 + l];
  }
  if (sl + 1 < hi) eB = edg[sl + 1];
  while (sl < hi) {
    // prefetch (independent of current compute): edge i+2 record, edge i+1 P value
    int4 eC = eB;
    if (sl + 2 < hi) eC = edg[sl + 2];
    float pN = pA;
    if (sl + 1 < hi) pN = P[(size_t)eB.x * 32 + l];
    // current edge: m for channel l
    const float ex = __int_as_float(eA.y), ey = __int_as_float(eA.z);
    const float m = fmaxf(0.f, fmaf(ex, wex, fmaf(ey, wey, pA)));
    ms += m;
    msl[l] = m;
    __builtin_amdgcn_wave_barrier();
    const float4 m0 = *reinterpret_cast<const float4*>(mrd + 0);
    const float4 m1 = *reinterpret_cast<const float4*>(mrd + 4);
    const float4 m2 = *reinterpret_cast<const float4*>(mrd + 8);
    const float4 m3 = *reinterpret_cast<const float4*>(mrd + 12);
    __builtin_amdgcn_wave_barrier();
    float zA0 = 0.f, zA1 = 0.f, zB0 = 0.f, zB1 = 0.f;
    zA0 = fmaf(m0.x, a0.x, zA0); zA1 = fmaf(m0.y, a0.y, zA1);
    zA0 = fmaf(m0.z, a0.z, zA0); zA1 = fmaf(m0.w, a0.w, zA1);
    zA0 = fmaf(m1.x, a1.x, zA0); zA1 = fmaf(m1.y, a1.y, zA1);
    zA0 = fmaf(m1.z, a1.z, zA0); zA1 = fmaf(m1.w, a1.w, zA1);
    zA0 = fmaf(m2.x, a2.x, zA0); zA1 = fmaf(m2.y, a2.y, zA1);
    zA0 = fmaf(m2.z, a2.z, zA0); zA1 = fmaf(m2.w, a2.w, zA1);
    zA0 = fmaf(m3.x, a3.x, zA0); zA1 = fmaf(m3.y, a3.y, zA1);
    zA0 = fmaf(m3.z, a3.z, zA0); zA1 = fmaf(m3.w, a3.w, zA1);
    zB0 = fmaf(m0.x, b0.x, zB0); zB1 = fmaf(m0.y, b0.y, zB1);
    zB0 = fmaf(m0.z, b0.z, zB0); zB1 = fmaf(m0.w, b0.w, zB1);
    zB0 = fmaf(m1.x, b1.x, zB0); zB1 = fmaf(m1.y, b1.y, zB1);
    zB0 = fmaf(m1.z, b1.z, zB0); zB1 = fmaf(m1.w, b1.w, zB1);
    zB0 = fmaf(m2.x, b2.x, zB0); zB1 = fmaf(m2.y, b2.y, zB1);
    zB0 = fmaf(m2.z, b2.z, zB0); zB1 = fmaf(m2.w, b2.w, zB1);
    zB0 = fmaf(m3.x, b3.x, zB0); zB1 = fmaf(m3.y, b3.y, zB1);
    zB0 = fmaf(m3.z, b3.z, zB0); zB1 = fmaf(m3.w, b3.w, zB1);
    float pAh = zA0 + zA1;
    float pBh = zB0 + zB1;
    pAh += __shfl_xor(pAh, 16, 64);
    pBh += __shfl_xor(pBh, 16, 64);
    const float z = ((l & 16) ? pBh : pAh) + bz;
    tz = fmaxf(tz, z);
    zq = fmaf(z, z, zq);
    // rotate pipeline
    eA = eB; eB = eC; pA = pN;
    ++sl;
  }
  // write per-node channel max (lane l -> tzb[n*32+l], coalesced per half)
  if (n < NN) tzb[(size_t)n * 32 + l] = tz;
  // stats: combine halves (same channel l), then block-reduce, then binned atomics
  float msT = ms + __shfl_xor(ms, 32, 64);
  float zqT = zq + __shfl_xor(zq, 32, 64);
  if (lane < 32) { redm[wid][l] = msT; redq[wid][l] = zqT; }
  __syncthreads();
  if (tid < 32) {
    float a = redm[0][tid] + redm[1][tid] + redm[2][tid] + redm[3][tid];
    float b = redq[0][tid] + redq[1][tid] + redq[2][tid] + redq[3][tid];
    const int bin = blockIdx.x & (NBIN - 1);
    unsafeAtomicAdd(&gms[bin * 32 + tid], a);
    unsafeAtomicAdd(&gzq[bin * 32 + tid], b);
  }
}

// layer-2 BN from binned stats: zs_j = w1b[:,j]·ms + E*b1b_j; A2d = A2*sign(g1b); zero bins
__global__ void k_fin2(float* __restrict__ gms, float* __restrict__ gzq,
    const float* __restrict__ w1b, const float* __restrict__ b1b,
    const float* __restrict__ g1b, const float* __restrict__ be1b,
    float* __restrict__ A2d, float* __restrict__ C2) {
  __shared__ float sm[32];
  int j = threadIdx.x;  // 32 threads
  float msj = 0.f, zqj = 0.f;
  for (int b = 0; b < NBIN; b++) { msj += gms[b * 32 + j]; zqj += gzq[b * 32 + j]; }
  sm[j] = msj;
  __syncthreads();
  float zs = EF * b1b[j];
  #pragma unroll
  for (int k = 0; k < 32; k++) zs = fmaf(w1b[k * 32 + j], sm[k], zs);
  const float invE = 1.f / EF;
  float mu = zs * invE;
  float var = fmaxf(zqj * invE - mu * mu, 0.f);
  float A = g1b[j] * rsqrtf(var + 1e-5f);
  float C = be1b[j] - mu * A;
  float d = (g1b[j] >= 0.f) ? 1.f : -1.f;
  A2d[j] = A * d; C2[j] = C;
  for (int b = 0; b < NBIN; b++) { gms[b * 32 + j] = 0.f; gzq[b * 32 + j] = 0.f; }
}

// BN finalize: a = g*rsqrt(var+eps), c = be - mu*a; zero sums for reuse
__global__ void k_finalize(float* __restrict__ sum, float* __restrict__ ssq,
                           const float* __restrict__ g, const float* __restrict__ be,
                           float inv_n, int ncols, float* __restrict__ a, float* __restrict__ c) {
  int j = threadIdx.x;
  if (j < ncols) {
    float mu = sum[j] * inv_n;
    float var = fmaxf(ssq[j] * inv_n - mu * mu, 0.f);
    float s = rsqrtf(var + 1e-5f) * g[j];
    a[j] = s; c[j] = be[j] - mu * s;
    sum[j] = 0.f; ssq[j] = 0.f;
  }
}

// ---------- agg finalize + h_pre = [x, agg] @ w2a + b2a (+stats) ----------

__global__ __launch_bounds__(256) void k_hpre2(const float* __restrict__ xp,
    const float* __restrict__ tzb, const int* __restrict__ starts,
    const float* __restrict__ A2d, const float* __restrict__ C2, const float* __restrict__ w2aT,
    float* __restrict__ hpre, float* __restrict__ gsum, float* __restrict__ gssq) {
  __shared__ float red[256];
  const int n = blockIdx.x * 256 + threadIdx.x;
  float h[32], hh[32];
  #pragma unroll
  for (int j = 0; j < 32; j++) h[j] = 0.f;
  if (n < NN) {
    float xv[11];
    loadrow(xp, n, xv);
    const int dg = starts[n + 1] - starts[n];
    float av[32];
    if (dg > 0) {
      const float4* tp = reinterpret_cast<const float4*>(tzb + (size_t)n * 32);
      #pragma unroll
      for (int j = 0; j < 8; j++) {
        float4 v = tp[j];
        av[4 * j]     = fmaxf(0.f, fmaf(A2d[4 * j],     v.x, C2[4 * j]));
        av[4 * j + 1] = fmaxf(0.f, fmaf(A2d[4 * j + 1], v.y, C2[4 * j + 1]));
        av[4 * j + 2] = fmaxf(0.f, fmaf(A2d[4 * j + 2], v.z, C2[4 * j + 2]));
        av[4 * j + 3] = fmaxf(0.f, fmaf(A2d[4 * j + 3], v.w, C2[4 * j + 3]));
      }
    } else {
      #pragma unroll
      for (int j = 0; j < 32; j++) av[j] = 0.f;
    }
    #pragma unroll
    for (int j = 0; j < 32; j++) {
      const float* wr = w2aT + j * 44;
      float acc = wr[43];
      #pragma unroll
      for (int k = 0; k < 11; k++) acc = fmaf(xv[k], wr[k], acc);
      #pragma unroll
      for (int k = 0; k < 32; k++) acc = fmaf(av[k], wr[11 + k], acc);
      h[j] = acc;
    }
    float4* hp = reinterpret_cast<float4*>(hpre + (size_t)n * 32);
    #pragma unroll
    for (int j = 0; j < 8; j++)
      hp[j] = make_float4(h[4 * j], h[4 * j + 1], h[4 * j + 2], h[4 * j + 3]);
  }
  #pragma unroll
  for (int j = 0; j < 32; j++) hh[j] = h[j] * h[j];
  reduce64(h, hh, red, gsum, gssq);
}

// comb = relu(relu(bn(h_pre)) @ w2b + b2b) -> xp col 10
__global__ __launch_bounds__(256) void k_comb(const float* __restrict__ hpre,
    const float* __restrict__ a3, const float* __restrict__ c3,
    const float* __restrict__ w2b, const float* __restrict__ b2b, float* __restrict__ xp) {
  const int n = blockIdx.x * 256 + threadIdx.x;
  if (n >= NN) return;
  const float4* hp = reinterpret_cast<const float4*>(hpre + (size_t)n * 32);
  float acc = b2b[0];
  #pragma unroll
  for (int j = 0; j < 8; j++) {
    float4 v = hp[j];
    acc += fmaxf(0.f, fmaf(v.x, a3[4 * j],     c3[4 * j]))     * w2b[4 * j];
    acc += fmaxf(0.f, fmaf(v.y, a3[4 * j + 1], c3[4 * j + 1])) * w2b[4 * j + 1];
    acc += fmaxf(0.f, fmaf(v.z, a3[4 * j + 2], c3[4 * j + 2])) * w2b[4 * j + 2];
    acc += fmaxf(0.f, fmaf(v.w, a3[4 * j + 3], c3[4 * j + 3])) * w2b[4 * j + 3];
  }
  xp[(size_t)n * 12 + 10] = fmaxf(acc, 0.f);
}

// ---------- power MLP ----------

// yp = x @ wpa + bpa : store to ybuf + stats
__global__ __launch_bounds__(256) void k_p5(const float* __restrict__ xp, const float* __restrict__ wpaT,
                                            float* __restrict__ ybuf,
                                            float* __restrict__ gsum, float* __restrict__ gssq) {
  __shared__ float red[256];
  const int n = blockIdx.x * 256 + threadIdx.x;
  float y[32], yy[32];
  #pragma unroll
  for (int j = 0; j < 32; j++) y[j] = 0.f;
  if (n < NN) {
    float xv[11];
    loadrow(xp, n, xv);
    #pragma unroll
    for (int j = 0; j < 32; j++) {
      const float* wr = wpaT + j * 12;
      float acc = wr[11];
      #pragma unroll
      for (int k = 0; k < 11; k++) acc = fmaf(xv[k], wr[k], acc);
      y[j] = acc;
    }
    float4* yp = reinterpret_cast<float4*>(ybuf + (size_t)n * 32);
    #pragma unroll
    for (int j = 0; j < 8; j++)
      yp[j] = make_float4(y[4 * j], y[4 * j + 1], y[4 * j + 2], y[4 * j + 3]);
  }
  #pragma unroll
  for (int j = 0; j < 32; j++) yy[j] = y[j] * y[j];
  reduce64(y, yy, red, gsum, gssq);
}

// yq = relu(bn(yp)) @ wpb + bpb : store + scalar stats (reads stored yp)
__global__ __launch_bounds__(256) void k_p6(const float* __restrict__ ybuf,
    const float* __restrict__ a4, const float* __restrict__ c4,
    const float* __restrict__ wpb, const float* __restrict__ bpb,
    float* __restrict__ yq, float* __restrict__ gsum, float* __restrict__ gssq) {
  __shared__ float red[8];
  const int n = blockIdx.x * 256 + threadIdx.x;
  float sum = 0.f, ssq = 0.f;
  if (n < NN) {
    const float4* yp = reinterpret_cast<const float4*>(ybuf + (size_t)n * 32);
    float q = bpb[0];
    #pragma unroll
    for (int j = 0; j < 8; j++) {
      float4 v = yp[j];
      q = fmaf(fmaxf(0.f, fmaf(v.x, a4[4 * j],     c4[4 * j])),     wpb[4 * j],     q);
      q = fmaf(fmaxf(0.f, fmaf(v.y, a4[4 * j + 1], c4[4 * j + 1])), wpb[4 * j + 1], q);
      q = fmaf(fmaxf(0.f, fmaf(v.z, a4[4 * j + 2], c4[4 * j + 2])), wpb[4 * j + 2], q);
      q = fmaf(fmaxf(0.f, fmaf(v.w, a4[4 * j + 3], c4[4 * j + 3])), wpb[4 * j + 3], q);
    }
    yq[n] = q;
    sum = q; ssq = q * q;
  }
  float s = wsum(sum), qq = wsum(ssq);
  const int wid = threadIdx.x >> 6, lane = threadIdx.x & 63;
  if (lane == 0) { red[wid] = s; red[4 + wid] = qq; }
  __syncthreads();
  if (threadIdx.x == 0) {
    unsafeAtomicAdd(&gsum[0], red[0] + red[1] + red[2] + red[3]);
    unsafeAtomicAdd(&gssq[0], red[4] + red[5] + red[6] + red[7]);
  }
}

__global__ __launch_bounds__(256) void k_p7(const float* __restrict__ yq,
    const float* __restrict__ a5, const float* __restrict__ c5, float* __restrict__ out) {
  int n = blockIdx.x * 256 + threadIdx.x;
  if (n < NN) out[n] = fmaxf(0.f, fmaf(yq[n], a5[0], c5[0]));
}

// ---------- host launch ----------

extern "C" void kernel_launch(void* const* d_in, const int* in_sizes, int n_in,
                              void* d_out, int out_size, void* d_ws, size_t ws_size,
                              hipStream_t stream) {
  const float* x    = (const float*)d_in[0];
  const float* ea   = (const float*)d_in[1];
  const int*   ei   = (const int*)d_in[2];
  const int*   srcp = ei;
  const int*   dstp = ei + EE;
  const float* w1a = (const float*)d_in[3],  *b1a = (const float*)d_in[4];
  const float* g1a = (const float*)d_in[5],  *be1a = (const float*)d_in[6];
  const float* w1b = (const float*)d_in[7],  *b1b = (const float*)d_in[8];
  const float* g1b = (const float*)d_in[9],  *be1b = (const float*)d_in[10];
  const float* w2a = (const float*)d_in[11], *b2a = (const float*)d_in[12];
  const float* g2a = (const float*)d_in[13], *be2a = (const float*)d_in[14];
  const float* w2b = (const float*)d_in[15], *b2b = (const float*)d_in[16];
  const float* wpa = (const float*)d_in[17], *bpa = (const float*)d_in[18];
  const float* gpa = (const float*)d_in[19], *bepa = (const float*)d_in[20];
  const float* wpb = (const float*)d_in[21], *bpb = (const float*)d_in[22];
  const float* gpb = (const float*)d_in[23], *bepb = (const float*)d_in[24];

  size_t off = 0;
  char* base = (char*)d_ws;
  auto alloc = [&](size_t bytes) -> void* {
    void* p = base + off;
    off += (bytes + 255) & ~(size_t)255;
    return p;
  };
  float* stats = (float*)alloc(2048);
  float* coef  = (float*)alloc(2048);
  float* mom   = (float*)alloc(512);
  float* cmom  = (float*)alloc(256);
  float* gmsB  = (float*)alloc(NBIN * 32 * 4);
  float* gzqB  = (float*)alloc(NBIN * 32 * 4);
  float* w1f   = (float*)alloc(16 * 32 * 4);
  float* wexy  = (float*)alloc(64 * 4);
  float* w2tf  = (float*)alloc(32 * 32 * 4);
  float* b1bf  = (float*)alloc(256);
  float* w2aT  = (float*)alloc(32 * 44 * 4);
  float* wpaT  = (float*)alloc(32 * 12 * 4);
  int*   cnt    = (int*)alloc(NN * 4);
  unsigned long long* nsd = (unsigned long long*)alloc((size_t)NN * 8);
  int*   starts = (int*)alloc((NN + 1) * 4);
  int*   rank   = (int*)alloc((size_t)EE * 4);
  int4*  edg    = (int4*)alloc((size_t)EE * 16);
  float* xp     = (float*)alloc((size_t)NN * 12 * 4);
  float* P      = (float*)alloc((size_t)NN * 32 * 4);
  float* tzb    = (float*)alloc((size_t)NN * 32 * 4);
  float* hpre   = (float*)alloc((size_t)NN * 32 * 4);
  float* yq     = (float*)alloc(NN * 4);

  float *SUM3 = stats + 64,  *SSQ3 = stats + 96;
  float *SUM4 = stats + 128, *SSQ4 = stats + 160;
  float *SUM5 = stats + 192, *SSQ5 = stats + 224;
  float *A2d = coef,       *C2 = coef + 32;
  float *A3  = coef + 64,  *C3 = coef + 96;
  float *A4  = coef + 128, *C4 = coef + 160;
  float *A5  = coef + 192, *C5 = coef + 224;

  hipMemsetAsync(stats, 0, 2048, stream);
  hipMemsetAsync(mom, 0, 512 + 256, stream);               // mom + cmom (contiguous)
  hipMemsetAsync(gmsB, 0, NBIN * 32 * 4 * 2, stream);      // gmsB + gzqB (contiguous)
  hipMemsetAsync(cnt, 0, NN * 4, stream);
  hipMemsetAsync(nsd, 0, (size_t)NN * 8, stream);

  const int GN = (NN + 255) / 256;          // 391
  const int GW = NN / 8;                    // 12500 blocks: 8 nodes x (4 waves x 2 halves)
  const int GE4 = (EE / 4 + 255) / 256;     // 3125

  k_wprep  <<<1, 256, 0, stream>>>(w1b, b1b, g1b, w2a, b2a, wpa, bpa, w2tf, b1bf, w2aT, wpaT);
  k_prep   <<<GE4, 256, 0, stream>>>(dstp, srcp, ea, cnt, rank, nsd, cmom);
  k_scan   <<<1, 1024, 0, stream>>>(cnt, starts);
  k_scatter<<<GE4, 256, 0, stream>>>(dstp, srcp, ea, starts, rank, edg);
  k_xp     <<<GN, 256, 0, stream>>>(x, xp);

  const float invN = 1.f / (float)NN;
  for (int c = 0; c < 3; c++) {
    k_mom     <<<GN, 256, 0, stream>>>(xp, nsd, mom);
    k_fin1    <<<1, 32, 0, stream>>>(mom, cmom, w1a, b1a, g1a, be1a, w1f, wexy);
    k_P       <<<GN, 256, 0, stream>>>(xp, w1f, P);
    k_fusedagg<<<GW, 256, 0, stream>>>(starts, edg, P, wexy, w2tf, b1bf, tzb, gmsB, gzqB);
    k_fin2    <<<1, 32, 0, stream>>>(gmsB, gzqB, w1b, b1b, g1b, be1b, A2d, C2);
    k_hpre2   <<<GN, 256, 0, stream>>>(xp, tzb, starts, A2d, C2, w2aT, hpre, SUM3, SSQ3);
    k_finalize<<<1, 32, 0, stream>>>(SUM3, SSQ3, g2a, be2a, invN, 32, A3, C3);
    k_comb    <<<GN, 256, 0, stream>>>(hpre, A3, C3, w2b, b2b, xp);
  }

  k_p5      <<<GN, 256, 0, stream>>>(xp, wpaT, hpre, SUM4, SSQ4);
  k_finalize<<<1, 32, 0, stream>>>(SUM4, SSQ4, gpa, bepa, invN, 32, A4, C4);
  k_p6      <<<GN, 256, 0, stream>>>(hpre, A4, C4, wpb, bpb, yq, SUM5, SSQ5);
  k_finalize<<<1, 32, 0, stream>>>(SUM5, SSQ5, gpb, bepb, invN, 1, A5, C5);
  k_p7      <<<GN, 256, 0, stream>>>(yq, A5, C5, (float*)d_out);
}